// Round 10
// baseline (403.890 us; speedup 1.0000x reference)
//
#include <hip/hip_runtime.h>
#include <hip/hip_bf16.h>
#include <math.h>

// Problem constants
static constexpr int kB = 256;
static constexpr int kL = 256;
static constexpr int kD = 100;
static constexpr int kLIN = 512;
static constexpr int SZ_E = kB * kL * kD;     // 6,553,600
static constexpr int W_FRAG = 7 * 8 * 64 * 8; // 28672 bf16 per layer

typedef short  s8_t  __attribute__((ext_vector_type(8)));
typedef float  f4_t  __attribute__((ext_vector_type(4)));

// sbf fragment storage (hi-only bf16): rowgroup g = row>>4, slot s in [0,4):
//   ((size_t)g*4 + s)*512 shorts, lane = quad*16 + (row&15), 8 shorts/lane,
//   k = s*32 + quad*8 + j (identity). sq from the SAME bf16-rounded values.
// W fragments pi-permuted (wprep); matchf's Dp registers are A-operand
// fragments in the same pi order, fed directly to the f-GEMM MFMA.

__device__ __forceinline__ unsigned short f2bf(float x) {
    __hip_bfloat16 h = __float2bfloat16(x);
    return *(unsigned short*)&h;
}
__device__ __forceinline__ float bf2f(unsigned short u) {
    unsigned int w = ((unsigned int)u) << 16;
    return *(float*)&w;
}
__device__ __forceinline__ float ftanh(float x) {
    float ax = fabsf(x);
    float t = __expf(-2.f * ax);
    float r = 1.f - 2.f * t / (1.f + t);
    return copysignf(r, x);
}

// write one rowgroup (16 rows in rb[16][104]) as 4 coalesced hi fragments (one per wave)
__device__ __forceinline__ void frag_store(const float (*rb)[104], const float* vsh,
                                           unsigned short* sb, int g, int tid) {
    int lane = tid & 63, wave = tid >> 6;   // wave = slot
    int qd = (lane >> 4) & 3, r15 = lane & 15;
    float v = vsh[r15];
    int kbase = wave * 32 + qd * 8;
    s8_t stv;
#pragma unroll
    for (int j = 0; j < 8; ++j) {
        int k = kbase + j;
        float x = (k < kD) ? rb[r15][k] * v : 0.f;
        stv[j] = (short)f2bf(x);
    }
    *(s8_t*)(sb + ((size_t)g * 4 + wave) * 512 + lane * 8) = stv;
}

// per-row sum of squares of bf16-ROUNDED masked values (16 threads/row)
__device__ __forceinline__ void sq_store(const float (*rb)[104], const float* vsh,
                                         float* sq, int row0, int tid) {
    int r = tid >> 4, j = tid & 15;
    float v = vsh[r];
    float s = 0.f;
    for (int d = j; d < kD; d += 16) { float x = bf2f(f2bf(rb[r][d] * v)); s += x * x; }
#pragma unroll
    for (int m = 8; m >= 1; m >>= 1) s += __shfl_xor(s, m, 64);
    if (j == 0) sq[row0 + r] = s;
}

// ------------------------------------------------------------- embed + prep + fused mean
__global__ __launch_bounds__(256) void embprep_kernel(const int* __restrict__ q1,
                                                      const int* __restrict__ q2,
                                                      const float* __restrict__ emb,
                                                      float* __restrict__ e1,
                                                      float* __restrict__ e2,
                                                      unsigned short* __restrict__ sbf1,
                                                      unsigned short* __restrict__ sbf2,
                                                      float* __restrict__ sq1,
                                                      float* __restrict__ sq2,
                                                      float* __restrict__ xcat) {
    __shared__ float rb[16][104];
    __shared__ float vsh[16];
    int side = blockIdx.y;
    const int* q = side ? q2 : q1;
    float* e = side ? e2 : e1;
    unsigned short* sb = side ? sbf2 : sbf1;
    float* sq = side ? sq2 : sq1;
    int tid = threadIdx.x;
    int row0 = blockIdx.x * 16;
    int b = row0 >> 8;
    if (tid < 16) vsh[tid] = (q[row0 + tid] != 0) ? 1.f : 0.f;
    for (int t = tid; t < 400; t += 256) {
        int r = t / 25, c = t - r * 25;
        int qv = q[row0 + r];
        float4 v4 = *(const float4*)(emb + (size_t)qv * kD + c * 4);
        *(float4*)(e + (size_t)(row0 + r) * kD + c * 4) = v4;
        *(float4*)&rb[r][c * 4] = v4;
    }
    __syncthreads();
    sq_store(rb, vsh, sq, row0, tid);
    if (tid < kD) {
        float s = 0.f;
#pragma unroll
        for (int r = 0; r < 16; ++r) s += rb[r][tid];
        atomicAdd(&xcat[b * 600 + side * 300 + tid], s * (1.0f / kL));
    }
    frag_store(rb, vsh, sb, row0 >> 4, tid);
}

// ------------------------------------------------------------- fused match + f-GEMM
__global__ __launch_bounds__(256) void matchf_kernel(const unsigned short* __restrict__ sbf1,
                                                     const unsigned short* __restrict__ sbf2,
                                                     const float* __restrict__ sq1,
                                                     const float* __restrict__ sq2,
                                                     const unsigned short* __restrict__ Wf,
                                                     unsigned short* __restrict__ f1,
                                                     unsigned short* __restrict__ f2) {
    __shared__ short lb[8 * 4 * 512];   // 32KB: contraction-side fragments
    int tid = threadIdx.x;
    int lane = tid & 63, wave = tid >> 6;
    int quad = lane >> 4, l15 = lane & 15;
    int side = blockIdx.y;
    int b = blockIdx.z;
    const unsigned short* sA = side ? sbf2 : sbf1;
    const unsigned short* sB = side ? sbf1 : sbf2;
    const float* sqA = side ? sq2 : sq1;
    const float* sqB = side ? sq1 : sq2;
    unsigned short* fo = side ? f2 : f1;
    int i0 = blockIdx.x * 128;
    int iw = i0 + wave * 32;
    int lo8 = lane * 8;

    const unsigned short* s1f = sA + ((size_t)(b * 16 + (iw >> 4)) * 4) * 512 + lo8;
    s8_t a1[2][4];
#pragma unroll
    for (int mt = 0; mt < 2; ++mt)
#pragma unroll
        for (int kt = 0; kt < 4; ++kt)
            a1[mt][kt] = *(const s8_t*)(s1f + (size_t)(mt * 4 + kt) * 512);

    float s1c[2] = { sqA[b * kL + iw + l15], sqA[b * kL + iw + 16 + l15] };
    const float* sq2p = sqB + b * kL;

    f4_t facc[2][7] = {};

    for (int jt = 0; jt < 2; ++jt) {
        int j0 = jt * 128;
        if (jt) __syncthreads();
        const unsigned short* s2base = sB + ((size_t)(b * 16 + (j0 >> 4)) * 4) * 512;
#pragma unroll
        for (int t = 0; t < 8; ++t) {
            int frag = wave * 8 + t;
            s8_t vld = *(const s8_t*)(s2base + (size_t)frag * 512 + lo8);
            *(s8_t*)(lb + frag * 512 + lo8) = vld;
        }
        __syncthreads();
#pragma unroll
        for (int half = 0; half < 2; ++half) {
            f4_t Dp[4][2] = {};
#pragma unroll
            for (int kt = 0; kt < 4; ++kt) {
                s8_t b2[4];
#pragma unroll
                for (int n = 0; n < 4; ++n)
                    b2[n] = *(const s8_t*)&lb[((half * 4 + n) * 4 + kt) * 512 + lo8];
#pragma unroll
                for (int n = 0; n < 4; ++n)
#pragma unroll
                    for (int mt = 0; mt < 2; ++mt)
                        Dp[n][mt] = __builtin_amdgcn_mfma_f32_16x16x32_bf16(b2[n], a1[mt][kt], Dp[n][mt], 0, 0, 0);
            }
#pragma unroll
            for (int np = 0; np < 2; ++np) {
                int ktj = (j0 >> 5) + half * 2 + np;
                const unsigned short* bp = Wf + (size_t)(ktj * 64 + lane) * 8;
#pragma unroll
                for (int mt = 0; mt < 2; ++mt) {
                    s8_t af;
#pragma unroll
                    for (int h2 = 0; h2 < 2; ++h2) {
                        int n = np * 2 + h2;
#pragma unroll
                        for (int r = 0; r < 4; ++r) {
                            float s2q = sq2p[j0 + half * 64 + n * 16 + quad * 4 + r];
                            float d2 = fmaxf(s2q + s1c[mt] - 2.f * Dp[n][mt][r], 0.f);
                            float av = __builtin_amdgcn_rcpf(1.f + __builtin_amdgcn_sqrtf(d2));
                            af[h2 * 4 + r] = (short)f2bf(av);
                        }
                    }
#pragma unroll
                    for (int nt = 0; nt < 7; ++nt) {
                        s8_t wv = *(const s8_t*)(bp + (size_t)nt * 8 * 64 * 8);
                        facc[mt][nt] = __builtin_amdgcn_mfma_f32_16x16x32_bf16(af, wv, facc[mt][nt], 0, 0, 0);
                    }
                }
            }
        }
    }
#pragma unroll
    for (int mt = 0; mt < 2; ++mt)
#pragma unroll
        for (int nt = 0; nt < 7; ++nt) {
            int col = nt * 16 + l15;
            if (col < kD) {
#pragma unroll
                for (int r = 0; r < 4; ++r) {
                    size_t row = (size_t)(b * kL) + iw + mt * 16 + quad * 4 + r;
                    fo[row * kD + col] = f2bf(facc[mt][nt][r]);
                }
            }
        }
}

// ------------------------------------------------------------- match row/col sums (pooling weights)
__global__ __launch_bounds__(256) void match_sums(const unsigned short* __restrict__ sbf1,
                                                  const unsigned short* __restrict__ sbf2,
                                                  const float* __restrict__ sq1,
                                                  const float* __restrict__ sq2,
                                                  float* __restrict__ w1,
                                                  float* __restrict__ w2) {
    __shared__ short lb[8 * 4 * 512];
    int tid = threadIdx.x;
    int lane = tid & 63, wave = tid >> 6;
    int quad = lane >> 4, l15 = lane & 15;
    int b = blockIdx.z;
    int i0 = blockIdx.y * 128, j0 = blockIdx.x * 128;
    int iw = i0 + wave * 32;
    int lo8 = lane * 8;

    const unsigned short* s2base = sbf2 + ((size_t)(b * 16 + (j0 >> 4)) * 4) * 512;
#pragma unroll
    for (int t = 0; t < 8; ++t) {
        int frag = wave * 8 + t;
        s8_t vld = *(const s8_t*)(s2base + (size_t)frag * 512 + lo8);
        *(s8_t*)(lb + frag * 512 + lo8) = vld;
    }

    const unsigned short* s1f = sbf1 + ((size_t)(b * 16 + (iw >> 4)) * 4) * 512 + lo8;
    const float* sq1p = sq1 + b * kL + iw;
    const float* sq2p = sq2 + b * kL + j0;

    float s1v[2][4];
#pragma unroll
    for (int mt = 0; mt < 2; ++mt)
#pragma unroll
        for (int r = 0; r < 4; ++r) s1v[mt][r] = sq1p[mt * 16 + quad * 4 + r];

    float rs_acc[2][4] = {{0.f,0.f,0.f,0.f},{0.f,0.f,0.f,0.f}};
    __syncthreads();

    for (int half = 0; half < 2; ++half) {
        f4_t D[2][4] = {};
#pragma unroll
        for (int kt = 0; kt < 4; ++kt) {
            s8_t a1h[2], b2h[4];
#pragma unroll
            for (int mt = 0; mt < 2; ++mt)
                a1h[mt] = *(const s8_t*)(s1f + (size_t)(mt * 4 + kt) * 512);
#pragma unroll
            for (int n = 0; n < 4; ++n)
                b2h[n] = *(const s8_t*)&lb[((half * 4 + n) * 4 + kt) * 512 + lo8];
#pragma unroll
            for (int mt = 0; mt < 2; ++mt)
#pragma unroll
                for (int n = 0; n < 4; ++n)
                    D[mt][n] = __builtin_amdgcn_mfma_f32_16x16x32_bf16(a1h[mt], b2h[n], D[mt][n], 0, 0, 0);
        }
#pragma unroll
        for (int n = 0; n < 4; ++n) {
            float s2vn = sq2p[half * 64 + n * 16 + l15];
            float cs = 0.f;
#pragma unroll
            for (int mt = 0; mt < 2; ++mt) {
#pragma unroll
                for (int r = 0; r < 4; ++r) {
                    float d2 = fmaxf(s1v[mt][r] + s2vn - 2.f * D[mt][n][r], 0.f);
                    float av = __builtin_amdgcn_rcpf(1.f + __builtin_amdgcn_sqrtf(d2));
                    rs_acc[mt][r] += av; cs += av;
                }
            }
            cs += __shfl_xor(cs, 16, 64);
            cs += __shfl_xor(cs, 32, 64);
            if (lane < 16) atomicAdd(&w2[b * kL + j0 + half * 64 + n * 16 + lane], cs);
        }
    }
#pragma unroll
    for (int mt = 0; mt < 2; ++mt)
#pragma unroll
        for (int r = 0; r < 4; ++r) {
            float v = rs_acc[mt][r];
            v += __shfl_xor(v, 1, 64);
            v += __shfl_xor(v, 2, 64);
            v += __shfl_xor(v, 4, 64);
            v += __shfl_xor(v, 8, 64);
            if (l15 == 0) atomicAdd(&w1[b * kL + iw + mt * 16 + quad * 4 + r], v);
        }
}

// ------------------------------------------------------------- W -> B-fragment layout (bf16, pi-permuted k)
__global__ __launch_bounds__(256) void wprep_kernel(const float* __restrict__ Ws,
                                                    unsigned short* __restrict__ Wf) {
    int layer = blockIdx.x;
    const float* W = Ws + layer * kL * kD;
    unsigned short* o = Wf + layer * W_FRAG;
    for (int t = threadIdx.x; t < W_FRAG; t += 256) {
        int j = t & 7, lane = (t >> 3) & 63, kt = (t >> 9) & 7, nt = t >> 12;
        int k = kt * 32 + (j >> 2) * 16 + ((lane >> 4) & 3) * 4 + (j & 3);  // pi
        int n = nt * 16 + (lane & 15);
        float v = (n < kD) ? W[k * kD + n] : 0.f;
        o[t] = f2bf(v);
    }
}

// ------------------------------------------------------------- conv(3x3, 2ch) + tanh + mean(1) [+ fused hi prep]
// LDS fully aligned: le/lf[r][c*4] = data[c*4]; column 25 (words 100..103) = zeros.
// d-1 / d+4 neighbors come from cross-lane shuffles in the compute phase.
__global__ __launch_bounds__(256) void conv_kernel(const float* __restrict__ e1,
                                                   const float* __restrict__ e2,
                                                   const unsigned short* __restrict__ f1,
                                                   const unsigned short* __restrict__ f2,
                                                   const float* __restrict__ ck,
                                                   const float* __restrict__ cb,
                                                   float* __restrict__ o1,
                                                   float* __restrict__ o2,
                                                   float* __restrict__ res,
                                                   int ro1, int ro2,
                                                   int do_prep, int do_store,
                                                   const int* __restrict__ q1,
                                                   const int* __restrict__ q2,
                                                   unsigned short* __restrict__ sbf1,
                                                   unsigned short* __restrict__ sbf2,
                                                   float* __restrict__ sq1,
                                                   float* __restrict__ sq2,
                                                   float* __restrict__ w1,
                                                   float* __restrict__ w2) {
    __shared__ float le[18][104];
    __shared__ float lf[18][104];
    __shared__ float pm[8][104];
    __shared__ float ksh[19];
    int tid = threadIdx.x;
    int b = blockIdx.y;
    int l0 = blockIdx.x * 16;
    int side = blockIdx.z;
    const float* e = side ? e2 : e1;
    const unsigned short* f = side ? f2 : f1;
    float* o = side ? o2 : o1;
    const int* q = side ? q2 : q1;
    unsigned short* sb = side ? sbf2 : sbf1;
    float* sq = side ? sq2 : sq1;
    float* w = side ? w2 : w1;
    int res_off = side ? ro2 : ro1;
    if (tid < 19) ksh[tid] = (tid < 18) ? ck[tid] : cb[0];
    if (do_prep && tid < 16) w[b * kL + l0 + tid] = 0.f;
    // aligned staging: 18 rows x 26 float4-slots per channel (slot 25 = zero pad)
    for (int t = tid; t < 936; t += 256) {
        int a = t >= 468;
        int tt = a ? t - 468 : t;
        int r = tt / 26, c = tt - r * 26;
        int l = l0 - 1 + r;
        float4 v = {0.f, 0.f, 0.f, 0.f};
        if (l >= 0 && l < kL && c < 25) {
            size_t base = ((size_t)b * kL + l) * kD + c * 4;
            if (!a) v = *(const float4*)(e + base);
            else { ushort4 u = *(const ushort4*)(f + base);
                   v.x = bf2f(u.x); v.y = bf2f(u.y); v.z = bf2f(u.z); v.w = bf2f(u.w); }
        }
        float* rowp = a ? lf[r] : le[r];
        *(float4*)&rowp[c * 4] = v;
    }
    __syncthreads();
    int rg = tid >> 5, c4 = tid & 31;
    bool act = c4 < 25;
    int d0 = c4 * 4;
    float m4[4] = {0.f, 0.f, 0.f, 0.f};
#pragma unroll
    for (int rr = 0; rr < 2; ++rr) {
        int r = rg * 2 + rr;
        float bias = ksh[18];
        float a0 = bias, a1 = bias, a2 = bias, a3 = bias;
#pragma unroll
        for (int ch = 0; ch < 2; ++ch) {
            const float (*L)[104] = ch ? lf : le;
            const float* kp = &ksh[ch * 9];
#pragma unroll
            for (int ky = 0; ky < 3; ++ky) {
                float4 v4 = {0.f, 0.f, 0.f, 0.f};
                if (c4 < 26) v4 = *(const float4*)&L[r + ky][d0];
                float lw = __shfl_up(v4.w, 1, 32);
                if (c4 == 0) lw = 0.f;
                float rn = __shfl_down(v4.x, 1, 32);
                float k0 = kp[ky * 3], k1 = kp[ky * 3 + 1], k2 = kp[ky * 3 + 2];
                a0 += k0 * lw   + k1 * v4.x + k2 * v4.y;
                a1 += k0 * v4.x + k1 * v4.y + k2 * v4.z;
                a2 += k0 * v4.y + k1 * v4.z + k2 * v4.w;
                a3 += k0 * v4.z + k1 * v4.w + k2 * rn;
            }
        }
        a0 = ftanh(a0); a1 = ftanh(a1); a2 = ftanh(a2); a3 = ftanh(a3);
        if (act) {
            if (do_store) {
                float4 st = {a0, a1, a2, a3};
                *(float4*)&o[((size_t)(b * kL) + l0 + r) * kD + d0] = st;
            }
            m4[0] += a0; m4[1] += a1; m4[2] += a2; m4[3] += a3;
        }
        if (do_prep) {
            int row = b * kL + l0 + r;
            float v = (q[row] != 0) ? 1.f : 0.f;
            ushort4 hi = {0, 0, 0, 0};
            float xr0 = 0.f, xr1 = 0.f, xr2 = 0.f, xr3 = 0.f;
            if (act) {
                hi.x = f2bf(a0 * v); xr0 = bf2f(hi.x);
                hi.y = f2bf(a1 * v); xr1 = bf2f(hi.y);
                hi.z = f2bf(a2 * v); xr2 = bf2f(hi.z);
                hi.w = f2bf(a3 * v); xr3 = bf2f(hi.w);
            }
            float srow = xr0 * xr0 + xr1 * xr1 + xr2 * xr2 + xr3 * xr3;
#pragma unroll
            for (int m = 16; m >= 1; m >>= 1) srow += __shfl_xor(srow, m, 32);
            if (c4 == 0) sq[row] = srow;
            int kt = c4 >> 3;
            int lfr = ((c4 >> 1) & 3) * 16 + (row & 15);
            unsigned short* p0 = sb + ((size_t)(row >> 4) * 4 + kt) * 512 + lfr * 8 + 4 * (c4 & 1);
            if (c4 < 32) *(ushort4*)p0 = hi;
        }
    }
    if (act) { float4 st = {m4[0], m4[1], m4[2], m4[3]}; *(float4*)&pm[rg][d0] = st; }
    __syncthreads();
    if (tid < kD) {
        float s = 0.f;
#pragma unroll
        for (int g = 0; g < 8; ++g) s += pm[g][tid];
        atomicAdd(&res[b * 600 + res_off + tid], s * (1.0f / kL));
    }
}

// ------------------------------------------------------------- fused: e += avgpool3(o*w); hi prep (16-row blocks)
__global__ __launch_bounds__(256) void poolprep_kernel(const float* __restrict__ o1,
                                                       const float* __restrict__ o2,
                                                       const float* __restrict__ w1_,
                                                       const float* __restrict__ w2_,
                                                       const int* __restrict__ q1,
                                                       const int* __restrict__ q2,
                                                       float* __restrict__ e1,
                                                       float* __restrict__ e2,
                                                       unsigned short* __restrict__ sbf1,
                                                       unsigned short* __restrict__ sbf2,
                                                       float* __restrict__ sq1,
                                                       float* __restrict__ sq2) {
    __shared__ float tb[18][104];
    __shared__ float xb[16][104];
    __shared__ float vsh[16];
    __shared__ float wsh[18];
    int side = blockIdx.y;
    const float* o = side ? o2 : o1;
    const float* w = side ? w2_ : w1_;
    const int* q = side ? q2 : q1;
    float* e = side ? e2 : e1;
    unsigned short* sb = side ? sbf2 : sbf1;
    float* sq = side ? sq2 : sq1;
    int tid = threadIdx.x;
    int row0 = blockIdx.x * 16;
    int l0 = row0 & (kL - 1);
    int base_b = row0 - l0;
    if (tid < 18) {
        int l = l0 - 1 + tid;
        wsh[tid] = (l >= 0 && l < kL) ? w[base_b + l] : 0.f;
    }
    if (tid < 16) vsh[tid] = (q[row0 + tid] != 0) ? 1.f : 0.f;
    __syncthreads();
    for (int t = tid; t < 450; t += 256) {
        int r = t / 25, c = t - r * 25;
        int l = l0 - 1 + r;
        float4 v4 = {0.f, 0.f, 0.f, 0.f};
        if (l >= 0 && l < kL) v4 = *(const float4*)(o + (size_t)(base_b + l) * kD + c * 4);
        float ww = wsh[r];
        tb[r][c * 4 + 0] = v4.x * ww;
        tb[r][c * 4 + 1] = v4.y * ww;
        tb[r][c * 4 + 2] = v4.z * ww;
        tb[r][c * 4 + 3] = v4.w * ww;
    }
    __syncthreads();
    for (int t = tid; t < 400; t += 256) {
        int r = t / 25, c = t - r * 25;
        float* ep = e + (size_t)(row0 + r) * kD + c * 4;
        float4 e4 = *(float4*)ep;
        float nx = e4.x + (tb[r][c * 4 + 0] + tb[r + 1][c * 4 + 0] + tb[r + 2][c * 4 + 0]) * (1.f / 3.f);
        float ny = e4.y + (tb[r][c * 4 + 1] + tb[r + 1][c * 4 + 1] + tb[r + 2][c * 4 + 1]) * (1.f / 3.f);
        float nz = e4.z + (tb[r][c * 4 + 2] + tb[r + 1][c * 4 + 2] + tb[r + 2][c * 4 + 2]) * (1.f / 3.f);
        float nw = e4.w + (tb[r][c * 4 + 3] + tb[r + 1][c * 4 + 3] + tb[r + 2][c * 4 + 3]) * (1.f / 3.f);
        float4 st = {nx, ny, nz, nw};
        *(float4*)ep = st;
        *(float4*)&xb[r][c * 4] = st;
    }
    __syncthreads();
    sq_store(xb, vsh, sq, row0, tid);
    frag_store(xb, vsh, sb, row0 >> 4, tid);
}

// ------------------------------------------------------------- head
__device__ __forceinline__ float block_sum(float v, float* red, int tid) {
#pragma unroll
    for (int m = 32; m >= 1; m >>= 1) v += __shfl_xor(v, m, 64);
    __syncthreads();
    if ((tid & 63) == 0) red[tid >> 6] = v;
    __syncthreads();
    return red[0] + red[1] + red[2] + red[3];
}

__global__ __launch_bounds__(256) void head_kernel(const float* __restrict__ xcat,
                                                   const float* __restrict__ fc1w,
                                                   const float* __restrict__ fc1b,
                                                   const float* __restrict__ lng,
                                                   const float* __restrict__ lnb,
                                                   const float* __restrict__ fc2w,
                                                   const float* __restrict__ fc2b,
                                                   float* __restrict__ out) {
    __shared__ float xr[600];
    __shared__ float red[4];
    int b = blockIdx.x, tid = threadIdx.x;
    for (int t = tid; t < 600; t += 256) xr[t] = xcat[b * 600 + t];
    __syncthreads();
    float h0 = fc1b[tid], h1 = fc1b[tid + 256];
    for (int k = 0; k < 600; ++k) {
        float xv = xr[k];
        h0 = fmaf(xv, fc1w[k * kLIN + tid], h0);
        h1 = fmaf(xv, fc1w[k * kLIN + tid + 256], h1);
    }
    float mu = block_sum(h0 + h1, red, tid) * (1.0f / kLIN);
    float d0 = h0 - mu, d1 = h1 - mu;
    float var = block_sum(d0 * d0 + d1 * d1, red, tid) * (1.0f / kLIN);
    float rstd = rsqrtf(var + 1e-5f);
    float n0 = d0 * rstd * lng[tid] + lnb[tid];
    float n1 = d1 * rstd * lng[tid + 256] + lnb[tid + 256];
    float r0 = fmaxf(n0, 0.f), r1 = fmaxf(n1, 0.f);
    float p0 = r0 * fc2w[tid * 2 + 0] + r1 * fc2w[(tid + 256) * 2 + 0];
    float p1 = r0 * fc2w[tid * 2 + 1] + r1 * fc2w[(tid + 256) * 2 + 1];
    float o0 = block_sum(p0, red, tid);
    float o1 = block_sum(p1, red, tid);
    if (tid == 0) { out[b * 2 + 0] = o0 + fc2b[0]; out[b * 2 + 1] = o1 + fc2b[1]; }
}

// ----------------------------------------------------------------------------
extern "C" void kernel_launch(void* const* d_in, const int* in_sizes, int n_in,
                              void* d_out, int out_size, void* d_ws, size_t ws_size,
                              hipStream_t stream) {
    const int*   q1   = (const int*)d_in[0];
    const int*   q2   = (const int*)d_in[1];
    const float* emb  = (const float*)d_in[2];
    const float* Ws   = (const float*)d_in[3];
    const float* ck   = (const float*)d_in[4];
    const float* cb   = (const float*)d_in[5];
    const float* fc1w = (const float*)d_in[6];
    const float* fc1b = (const float*)d_in[7];
    const float* lng  = (const float*)d_in[8];
    const float* lnb  = (const float*)d_in[9];
    const float* fc2w = (const float*)d_in[10];
    const float* fc2b = (const float*)d_in[11];
    float* out = (float*)d_out;
    float* ws  = (float*)d_ws;

    float* e1  = ws;
    float* e2  = e1 + SZ_E;
    unsigned short* fb1 = (unsigned short*)(e2 + SZ_E);   // f1|f2 bf16 = SZ_E floats total
    unsigned short* fb2 = fb1 + SZ_E;
    float* o1  = (float*)fb1 + SZ_E;
    float* o2  = o1 + SZ_E;
    unsigned short* sbf1 = (unsigned short*)(o2 + SZ_E);  // hi-only fragments, 2 sides
    unsigned short* sbf2 = sbf1 + kB * kL * 128;
    float* after = (float*)sbf1 + kB * kL * 128;
    unsigned short* Wfrag = (unsigned short*)after;
    float* sq1 = after + W_FRAG;
    float* sq2 = sq1 + kB * kL;
    float* w1  = sq2 + kB * kL;
    float* w2  = w1 + kB * kL;
    float* xcat = w2 + kB * kL;

    hipMemsetAsync(xcat, 0, kB * 600 * sizeof(float), stream);
    embprep_kernel<<<dim3(kB * kL / 16, 2), 256, 0, stream>>>(q1, q2, emb, e1, e2,
                                                              sbf1, sbf2, sq1, sq2, xcat);
    wprep_kernel<<<2, 256, 0, stream>>>(Ws, Wfrag);

    // ---- layer 0
    matchf_kernel<<<dim3(2, 2, kB), 256, 0, stream>>>(sbf1, sbf2, sq1, sq2, Wfrag, fb1, fb2);
    conv_kernel<<<dim3(kL / 16, kB, 2), 256, 0, stream>>>(e1, e2, fb1, fb2, ck, cb,
                                                          o1, o2, xcat, 100, 400,
                                                          1, 1, q1, q2, sbf1, sbf2, sq1, sq2, w1, w2);
    match_sums<<<dim3(2, 2, kB), 256, 0, stream>>>(sbf1, sbf2, sq1, sq2, w1, w2);
    poolprep_kernel<<<dim3(kB * kL / 16, 2), 256, 0, stream>>>(o1, o2, w1, w2, q1, q2,
                                                               e1, e2, sbf1, sbf2, sq1, sq2);
    // ---- layer 1 (tail match/pool dead; o-store also dead)
    matchf_kernel<<<dim3(2, 2, kB), 256, 0, stream>>>(sbf1, sbf2, sq1, sq2, Wfrag + W_FRAG, fb1, fb2);
    conv_kernel<<<dim3(kL / 16, kB, 2), 256, 0, stream>>>(e1, e2, fb1, fb2, ck + 18, cb + 1,
                                                          o1, o2, xcat, 200, 500,
                                                          0, 0, q1, q2, sbf1, sbf2, sq1, sq2, w1, w2);

    head_kernel<<<kB, 256, 0, stream>>>(xcat, fc1w, fc1b, lng, lnb, fc2w, fc2b, out);
}

// Round 11
// 384.274 us; speedup vs baseline: 1.0510x; 1.0510x over previous
//
#include <hip/hip_runtime.h>
#include <hip/hip_bf16.h>
#include <math.h>

// Problem constants
static constexpr int kB = 256;
static constexpr int kL = 256;
static constexpr int kD = 100;
static constexpr int kLIN = 512;
static constexpr int SZ_E = kB * kL * kD;     // 6,553,600
static constexpr int W_FRAG = 7 * 8 * 64 * 8; // 28672 bf16 per layer

typedef short  s8_t  __attribute__((ext_vector_type(8)));
typedef float  f4_t  __attribute__((ext_vector_type(4)));

// sbf fragment storage (hi-only bf16): rowgroup g = row>>4, slot s in [0,4):
//   ((size_t)g*4 + s)*512 shorts, lane = quad*16 + (row&15), 8 shorts/lane,
//   k = s*32 + quad*8 + j (identity). sq from the SAME bf16-rounded values.
// W fragments pi-permuted (wprep); matchf's Dp registers are A-operand
// fragments in the same pi order, fed directly to the f-GEMM MFMA.
// NOTE (r10 post-mortem): conv uses the round-8 halo-LDS variant — the
// bank-conflict-free shuffle variant was SLOWER (VALU + VGPR pressure).

__device__ __forceinline__ unsigned short f2bf(float x) {
    __hip_bfloat16 h = __float2bfloat16(x);
    return *(unsigned short*)&h;
}
__device__ __forceinline__ float bf2f(unsigned short u) {
    unsigned int w = ((unsigned int)u) << 16;
    return *(float*)&w;
}
__device__ __forceinline__ float ftanh(float x) {
    float ax = fabsf(x);
    float t = __expf(-2.f * ax);
    float r = 1.f - 2.f * t / (1.f + t);
    return copysignf(r, x);
}

// write one rowgroup (16 rows in rb[16][104]) as 4 coalesced hi fragments (one per wave)
__device__ __forceinline__ void frag_store(const float (*rb)[104], const float* vsh,
                                           unsigned short* sb, int g, int tid) {
    int lane = tid & 63, wave = tid >> 6;   // wave = slot
    int qd = (lane >> 4) & 3, r15 = lane & 15;
    float v = vsh[r15];
    int kbase = wave * 32 + qd * 8;
    s8_t stv;
#pragma unroll
    for (int j = 0; j < 8; ++j) {
        int k = kbase + j;
        float x = (k < kD) ? rb[r15][k] * v : 0.f;
        stv[j] = (short)f2bf(x);
    }
    *(s8_t*)(sb + ((size_t)g * 4 + wave) * 512 + lane * 8) = stv;
}

// per-row sum of squares of bf16-ROUNDED masked values (16 threads/row)
__device__ __forceinline__ void sq_store(const float (*rb)[104], const float* vsh,
                                         float* sq, int row0, int tid) {
    int r = tid >> 4, j = tid & 15;
    float v = vsh[r];
    float s = 0.f;
    for (int d = j; d < kD; d += 16) { float x = bf2f(f2bf(rb[r][d] * v)); s += x * x; }
#pragma unroll
    for (int m = 8; m >= 1; m >>= 1) s += __shfl_xor(s, m, 64);
    if (j == 0) sq[row0 + r] = s;
}

// ------------------------------------------------------------- embed + prep + fused mean
__global__ __launch_bounds__(256) void embprep_kernel(const int* __restrict__ q1,
                                                      const int* __restrict__ q2,
                                                      const float* __restrict__ emb,
                                                      float* __restrict__ e1,
                                                      float* __restrict__ e2,
                                                      unsigned short* __restrict__ sbf1,
                                                      unsigned short* __restrict__ sbf2,
                                                      float* __restrict__ sq1,
                                                      float* __restrict__ sq2,
                                                      float* __restrict__ xcat) {
    __shared__ float rb[16][104];
    __shared__ float vsh[16];
    int side = blockIdx.y;
    const int* q = side ? q2 : q1;
    float* e = side ? e2 : e1;
    unsigned short* sb = side ? sbf2 : sbf1;
    float* sq = side ? sq2 : sq1;
    int tid = threadIdx.x;
    int row0 = blockIdx.x * 16;
    int b = row0 >> 8;
    if (tid < 16) vsh[tid] = (q[row0 + tid] != 0) ? 1.f : 0.f;
    for (int t = tid; t < 400; t += 256) {
        int r = t / 25, c = t - r * 25;
        int qv = q[row0 + r];
        float4 v4 = *(const float4*)(emb + (size_t)qv * kD + c * 4);
        *(float4*)(e + (size_t)(row0 + r) * kD + c * 4) = v4;
        *(float4*)&rb[r][c * 4] = v4;
    }
    __syncthreads();
    sq_store(rb, vsh, sq, row0, tid);
    if (tid < kD) {
        float s = 0.f;
#pragma unroll
        for (int r = 0; r < 16; ++r) s += rb[r][tid];
        atomicAdd(&xcat[b * 600 + side * 300 + tid], s * (1.0f / kL));
    }
    frag_store(rb, vsh, sb, row0 >> 4, tid);
}

// ------------------------------------------------------------- fused match + f-GEMM
__global__ __launch_bounds__(256) void matchf_kernel(const unsigned short* __restrict__ sbf1,
                                                     const unsigned short* __restrict__ sbf2,
                                                     const float* __restrict__ sq1,
                                                     const float* __restrict__ sq2,
                                                     const unsigned short* __restrict__ Wf,
                                                     unsigned short* __restrict__ f1,
                                                     unsigned short* __restrict__ f2) {
    __shared__ short lb[8 * 4 * 512];   // 32KB: contraction-side fragments
    int tid = threadIdx.x;
    int lane = tid & 63, wave = tid >> 6;
    int quad = lane >> 4, l15 = lane & 15;
    int side = blockIdx.y;
    int b = blockIdx.z;
    const unsigned short* sA = side ? sbf2 : sbf1;
    const unsigned short* sB = side ? sbf1 : sbf2;
    const float* sqA = side ? sq2 : sq1;
    const float* sqB = side ? sq1 : sq2;
    unsigned short* fo = side ? f2 : f1;
    int i0 = blockIdx.x * 128;
    int iw = i0 + wave * 32;
    int lo8 = lane * 8;

    const unsigned short* s1f = sA + ((size_t)(b * 16 + (iw >> 4)) * 4) * 512 + lo8;
    s8_t a1[2][4];
#pragma unroll
    for (int mt = 0; mt < 2; ++mt)
#pragma unroll
        for (int kt = 0; kt < 4; ++kt)
            a1[mt][kt] = *(const s8_t*)(s1f + (size_t)(mt * 4 + kt) * 512);

    float s1c[2] = { sqA[b * kL + iw + l15], sqA[b * kL + iw + 16 + l15] };
    const float* sq2p = sqB + b * kL;

    f4_t facc[2][7] = {};

    for (int jt = 0; jt < 2; ++jt) {
        int j0 = jt * 128;
        if (jt) __syncthreads();
        const unsigned short* s2base = sB + ((size_t)(b * 16 + (j0 >> 4)) * 4) * 512;
#pragma unroll
        for (int t = 0; t < 8; ++t) {
            int frag = wave * 8 + t;
            s8_t vld = *(const s8_t*)(s2base + (size_t)frag * 512 + lo8);
            *(s8_t*)(lb + frag * 512 + lo8) = vld;
        }
        __syncthreads();
#pragma unroll
        for (int half = 0; half < 2; ++half) {
            f4_t Dp[4][2] = {};
#pragma unroll
            for (int kt = 0; kt < 4; ++kt) {
                s8_t b2[4];
#pragma unroll
                for (int n = 0; n < 4; ++n)
                    b2[n] = *(const s8_t*)&lb[((half * 4 + n) * 4 + kt) * 512 + lo8];
#pragma unroll
                for (int n = 0; n < 4; ++n)
#pragma unroll
                    for (int mt = 0; mt < 2; ++mt)
                        Dp[n][mt] = __builtin_amdgcn_mfma_f32_16x16x32_bf16(b2[n], a1[mt][kt], Dp[n][mt], 0, 0, 0);
            }
#pragma unroll
            for (int np = 0; np < 2; ++np) {
                int ktj = (j0 >> 5) + half * 2 + np;
                const unsigned short* bp = Wf + (size_t)(ktj * 64 + lane) * 8;
#pragma unroll
                for (int mt = 0; mt < 2; ++mt) {
                    s8_t af;
#pragma unroll
                    for (int h2 = 0; h2 < 2; ++h2) {
                        int n = np * 2 + h2;
#pragma unroll
                        for (int r = 0; r < 4; ++r) {
                            float s2q = sq2p[j0 + half * 64 + n * 16 + quad * 4 + r];
                            float d2 = fmaxf(s2q + s1c[mt] - 2.f * Dp[n][mt][r], 0.f);
                            float av = __builtin_amdgcn_rcpf(1.f + __builtin_amdgcn_sqrtf(d2));
                            af[h2 * 4 + r] = (short)f2bf(av);
                        }
                    }
#pragma unroll
                    for (int nt = 0; nt < 7; ++nt) {
                        s8_t wv = *(const s8_t*)(bp + (size_t)nt * 8 * 64 * 8);
                        facc[mt][nt] = __builtin_amdgcn_mfma_f32_16x16x32_bf16(af, wv, facc[mt][nt], 0, 0, 0);
                    }
                }
            }
        }
    }
#pragma unroll
    for (int mt = 0; mt < 2; ++mt)
#pragma unroll
        for (int nt = 0; nt < 7; ++nt) {
            int col = nt * 16 + l15;
            if (col < kD) {
#pragma unroll
                for (int r = 0; r < 4; ++r) {
                    size_t row = (size_t)(b * kL) + iw + mt * 16 + quad * 4 + r;
                    fo[row * kD + col] = f2bf(facc[mt][nt][r]);
                }
            }
        }
}

// ------------------------------------------------------------- match row/col sums (pooling weights)
__global__ __launch_bounds__(256) void match_sums(const unsigned short* __restrict__ sbf1,
                                                  const unsigned short* __restrict__ sbf2,
                                                  const float* __restrict__ sq1,
                                                  const float* __restrict__ sq2,
                                                  float* __restrict__ w1,
                                                  float* __restrict__ w2) {
    __shared__ short lb[8 * 4 * 512];
    int tid = threadIdx.x;
    int lane = tid & 63, wave = tid >> 6;
    int quad = lane >> 4, l15 = lane & 15;
    int b = blockIdx.z;
    int i0 = blockIdx.y * 128, j0 = blockIdx.x * 128;
    int iw = i0 + wave * 32;
    int lo8 = lane * 8;

    const unsigned short* s2base = sbf2 + ((size_t)(b * 16 + (j0 >> 4)) * 4) * 512;
#pragma unroll
    for (int t = 0; t < 8; ++t) {
        int frag = wave * 8 + t;
        s8_t vld = *(const s8_t*)(s2base + (size_t)frag * 512 + lo8);
        *(s8_t*)(lb + frag * 512 + lo8) = vld;
    }

    const unsigned short* s1f = sbf1 + ((size_t)(b * 16 + (iw >> 4)) * 4) * 512 + lo8;
    const float* sq1p = sq1 + b * kL + iw;
    const float* sq2p = sq2 + b * kL + j0;

    float s1v[2][4];
#pragma unroll
    for (int mt = 0; mt < 2; ++mt)
#pragma unroll
        for (int r = 0; r < 4; ++r) s1v[mt][r] = sq1p[mt * 16 + quad * 4 + r];

    float rs_acc[2][4] = {{0.f,0.f,0.f,0.f},{0.f,0.f,0.f,0.f}};
    __syncthreads();

    for (int half = 0; half < 2; ++half) {
        f4_t D[2][4] = {};
#pragma unroll
        for (int kt = 0; kt < 4; ++kt) {
            s8_t a1h[2], b2h[4];
#pragma unroll
            for (int mt = 0; mt < 2; ++mt)
                a1h[mt] = *(const s8_t*)(s1f + (size_t)(mt * 4 + kt) * 512);
#pragma unroll
            for (int n = 0; n < 4; ++n)
                b2h[n] = *(const s8_t*)&lb[((half * 4 + n) * 4 + kt) * 512 + lo8];
#pragma unroll
            for (int mt = 0; mt < 2; ++mt)
#pragma unroll
                for (int n = 0; n < 4; ++n)
                    D[mt][n] = __builtin_amdgcn_mfma_f32_16x16x32_bf16(a1h[mt], b2h[n], D[mt][n], 0, 0, 0);
        }
#pragma unroll
        for (int n = 0; n < 4; ++n) {
            float s2vn = sq2p[half * 64 + n * 16 + l15];
            float cs = 0.f;
#pragma unroll
            for (int mt = 0; mt < 2; ++mt) {
#pragma unroll
                for (int r = 0; r < 4; ++r) {
                    float d2 = fmaxf(s1v[mt][r] + s2vn - 2.f * D[mt][n][r], 0.f);
                    float av = __builtin_amdgcn_rcpf(1.f + __builtin_amdgcn_sqrtf(d2));
                    rs_acc[mt][r] += av; cs += av;
                }
            }
            cs += __shfl_xor(cs, 16, 64);
            cs += __shfl_xor(cs, 32, 64);
            if (lane < 16) atomicAdd(&w2[b * kL + j0 + half * 64 + n * 16 + lane], cs);
        }
    }
#pragma unroll
    for (int mt = 0; mt < 2; ++mt)
#pragma unroll
        for (int r = 0; r < 4; ++r) {
            float v = rs_acc[mt][r];
            v += __shfl_xor(v, 1, 64);
            v += __shfl_xor(v, 2, 64);
            v += __shfl_xor(v, 4, 64);
            v += __shfl_xor(v, 8, 64);
            if (l15 == 0) atomicAdd(&w1[b * kL + iw + mt * 16 + quad * 4 + r], v);
        }
}

// ------------------------------------------------------------- W -> B-fragment layout (bf16, pi-permuted k)
__global__ __launch_bounds__(256) void wprep_kernel(const float* __restrict__ Ws,
                                                    unsigned short* __restrict__ Wf) {
    int layer = blockIdx.x;
    const float* W = Ws + layer * kL * kD;
    unsigned short* o = Wf + layer * W_FRAG;
    for (int t = threadIdx.x; t < W_FRAG; t += 256) {
        int j = t & 7, lane = (t >> 3) & 63, kt = (t >> 9) & 7, nt = t >> 12;
        int k = kt * 32 + (j >> 2) * 16 + ((lane >> 4) & 3) * 4 + (j & 3);  // pi
        int n = nt * 16 + (lane & 15);
        float v = (n < kD) ? W[k * kD + n] : 0.f;
        o[t] = f2bf(v);
    }
}

// ------------------------------------------------------------- conv(3x3, 2ch) + tanh + mean(1) [+ fused hi prep]
// round-8 variant: halo LDS layout [r][1+d], empirically fastest (bank
// conflicts at this level are cheaper than shuffle VALU + VGPR pressure).
__global__ __launch_bounds__(256) void conv_kernel(const float* __restrict__ e1,
                                                   const float* __restrict__ e2,
                                                   const unsigned short* __restrict__ f1,
                                                   const unsigned short* __restrict__ f2,
                                                   const float* __restrict__ ck,
                                                   const float* __restrict__ cb,
                                                   float* __restrict__ o1,
                                                   float* __restrict__ o2,
                                                   float* __restrict__ res,
                                                   int ro1, int ro2,
                                                   int do_prep, int do_store,
                                                   const int* __restrict__ q1,
                                                   const int* __restrict__ q2,
                                                   unsigned short* __restrict__ sbf1,
                                                   unsigned short* __restrict__ sbf2,
                                                   float* __restrict__ sq1,
                                                   float* __restrict__ sq2,
                                                   float* __restrict__ w1,
                                                   float* __restrict__ w2) {
    __shared__ float le[18][104];
    __shared__ float lf[18][104];
    __shared__ float pm[8][104];
    __shared__ float ksh[19];
    int tid = threadIdx.x;
    int b = blockIdx.y;
    int l0 = blockIdx.x * 16;
    int side = blockIdx.z;
    const float* e = side ? e2 : e1;
    const unsigned short* f = side ? f2 : f1;
    float* o = side ? o2 : o1;
    const int* q = side ? q2 : q1;
    unsigned short* sb = side ? sbf2 : sbf1;
    float* sq = side ? sq2 : sq1;
    float* w = side ? w2 : w1;
    int res_off = side ? ro2 : ro1;
    if (tid < 19) ksh[tid] = (tid < 18) ? ck[tid] : cb[0];
    if (tid < 18) { le[tid][0] = 0.f; lf[tid][0] = 0.f; le[tid][101] = 0.f; lf[tid][101] = 0.f; }
    if (do_prep && tid < 16) w[b * kL + l0 + tid] = 0.f;
    for (int t = tid; t < 900; t += 256) {
        int a = t >= 450;
        int tt = a ? t - 450 : t;
        int r = tt / 25, c = tt - r * 25;
        int l = l0 - 1 + r;
        bool ok = (l >= 0 && l < kL);
        size_t base = ((size_t)b * kL + (ok ? l : 0)) * kD + c * 4;
        float vx = 0.f, vy = 0.f, vz = 0.f, vw = 0.f;
        if (!a) {
            if (ok) { float4 v = *(const float4*)(e + base); vx = v.x; vy = v.y; vz = v.z; vw = v.w; }
            le[r][1 + c * 4] = vx; le[r][2 + c * 4] = vy; le[r][3 + c * 4] = vz; le[r][4 + c * 4] = vw;
        } else {
            if (ok) { ushort4 u = *(const ushort4*)(f + base); vx = bf2f(u.x); vy = bf2f(u.y); vz = bf2f(u.z); vw = bf2f(u.w); }
            lf[r][1 + c * 4] = vx; lf[r][2 + c * 4] = vy; lf[r][3 + c * 4] = vz; lf[r][4 + c * 4] = vw;
        }
    }
    __syncthreads();
    int rg = tid >> 5, c4 = tid & 31;
    bool act = c4 < 25;
    int d0 = c4 * 4;
    float m4[4] = {0.f, 0.f, 0.f, 0.f};
#pragma unroll
    for (int rr = 0; rr < 2; ++rr) {
        int r = rg * 2 + rr;
        float a0 = 0.f, a1 = 0.f, a2 = 0.f, a3 = 0.f;
        if (act) {
            float bias = ksh[18];
            a0 = bias; a1 = bias; a2 = bias; a3 = bias;
#pragma unroll
            for (int ch = 0; ch < 2; ++ch) {
                const float (*L)[104] = ch ? lf : le;
                const float* kp = &ksh[ch * 9];
#pragma unroll
                for (int ky = 0; ky < 3; ++ky) {
                    const float* row = L[r + ky];
                    float4 v4 = *(const float4*)&row[d0];
                    float2 v2 = *(const float2*)&row[d0 + 4];
                    float k0 = kp[ky * 3], k1 = kp[ky * 3 + 1], k2 = kp[ky * 3 + 2];
                    a0 += k0 * v4.x + k1 * v4.y + k2 * v4.z;
                    a1 += k0 * v4.y + k1 * v4.z + k2 * v4.w;
                    a2 += k0 * v4.z + k1 * v4.w + k2 * v2.x;
                    a3 += k0 * v4.w + k1 * v2.x + k2 * v2.y;
                }
            }
            a0 = ftanh(a0); a1 = ftanh(a1); a2 = ftanh(a2); a3 = ftanh(a3);
            if (do_store) {
                float4 st = {a0, a1, a2, a3};
                *(float4*)&o[((size_t)(b * kL) + l0 + r) * kD + d0] = st;
            }
            m4[0] += a0; m4[1] += a1; m4[2] += a2; m4[3] += a3;
        }
        if (do_prep) {
            int row = b * kL + l0 + r;
            float v = (q[row] != 0) ? 1.f : 0.f;
            ushort4 hi = {0, 0, 0, 0};
            float xr0 = 0.f, xr1 = 0.f, xr2 = 0.f, xr3 = 0.f;
            if (act) {
                hi.x = f2bf(a0 * v); xr0 = bf2f(hi.x);
                hi.y = f2bf(a1 * v); xr1 = bf2f(hi.y);
                hi.z = f2bf(a2 * v); xr2 = bf2f(hi.z);
                hi.w = f2bf(a3 * v); xr3 = bf2f(hi.w);
            }
            float srow = xr0 * xr0 + xr1 * xr1 + xr2 * xr2 + xr3 * xr3;
#pragma unroll
            for (int m = 16; m >= 1; m >>= 1) srow += __shfl_xor(srow, m, 32);
            if (c4 == 0) sq[row] = srow;
            int kt = c4 >> 3;
            int lfr = ((c4 >> 1) & 3) * 16 + (row & 15);
            unsigned short* p0 = sb + ((size_t)(row >> 4) * 4 + kt) * 512 + lfr * 8 + 4 * (c4 & 1);
            *(ushort4*)p0 = hi;
        }
    }
    if (act) { float4 st = {m4[0], m4[1], m4[2], m4[3]}; *(float4*)&pm[rg][d0] = st; }
    __syncthreads();
    if (tid < kD) {
        float s = 0.f;
#pragma unroll
        for (int g = 0; g < 8; ++g) s += pm[g][tid];
        atomicAdd(&res[b * 600 + res_off + tid], s * (1.0f / kL));
    }
}

// ------------------------------------------------------------- fused: e += avgpool3(o*w); hi prep (16-row blocks)
__global__ __launch_bounds__(256) void poolprep_kernel(const float* __restrict__ o1,
                                                       const float* __restrict__ o2,
                                                       const float* __restrict__ w1_,
                                                       const float* __restrict__ w2_,
                                                       const int* __restrict__ q1,
                                                       const int* __restrict__ q2,
                                                       float* __restrict__ e1,
                                                       float* __restrict__ e2,
                                                       unsigned short* __restrict__ sbf1,
                                                       unsigned short* __restrict__ sbf2,
                                                       float* __restrict__ sq1,
                                                       float* __restrict__ sq2) {
    __shared__ float tb[18][104];
    __shared__ float xb[16][104];
    __shared__ float vsh[16];
    __shared__ float wsh[18];
    int side = blockIdx.y;
    const float* o = side ? o2 : o1;
    const float* w = side ? w2_ : w1_;
    const int* q = side ? q2 : q1;
    float* e = side ? e2 : e1;
    unsigned short* sb = side ? sbf2 : sbf1;
    float* sq = side ? sq2 : sq1;
    int tid = threadIdx.x;
    int row0 = blockIdx.x * 16;
    int l0 = row0 & (kL - 1);
    int base_b = row0 - l0;
    if (tid < 18) {
        int l = l0 - 1 + tid;
        wsh[tid] = (l >= 0 && l < kL) ? w[base_b + l] : 0.f;
    }
    if (tid < 16) vsh[tid] = (q[row0 + tid] != 0) ? 1.f : 0.f;
    __syncthreads();
    for (int t = tid; t < 450; t += 256) {
        int r = t / 25, c = t - r * 25;
        int l = l0 - 1 + r;
        float4 v4 = {0.f, 0.f, 0.f, 0.f};
        if (l >= 0 && l < kL) v4 = *(const float4*)(o + (size_t)(base_b + l) * kD + c * 4);
        float ww = wsh[r];
        tb[r][c * 4 + 0] = v4.x * ww;
        tb[r][c * 4 + 1] = v4.y * ww;
        tb[r][c * 4 + 2] = v4.z * ww;
        tb[r][c * 4 + 3] = v4.w * ww;
    }
    __syncthreads();
    for (int t = tid; t < 400; t += 256) {
        int r = t / 25, c = t - r * 25;
        float* ep = e + (size_t)(row0 + r) * kD + c * 4;
        float4 e4 = *(float4*)ep;
        float nx = e4.x + (tb[r][c * 4 + 0] + tb[r + 1][c * 4 + 0] + tb[r + 2][c * 4 + 0]) * (1.f / 3.f);
        float ny = e4.y + (tb[r][c * 4 + 1] + tb[r + 1][c * 4 + 1] + tb[r + 2][c * 4 + 1]) * (1.f / 3.f);
        float nz = e4.z + (tb[r][c * 4 + 2] + tb[r + 1][c * 4 + 2] + tb[r + 2][c * 4 + 2]) * (1.f / 3.f);
        float nw = e4.w + (tb[r][c * 4 + 3] + tb[r + 1][c * 4 + 3] + tb[r + 2][c * 4 + 3]) * (1.f / 3.f);
        float4 st = {nx, ny, nz, nw};
        *(float4*)ep = st;
        *(float4*)&xb[r][c * 4] = st;
    }
    __syncthreads();
    sq_store(xb, vsh, sq, row0, tid);
    frag_store(xb, vsh, sb, row0 >> 4, tid);
}

// ------------------------------------------------------------- head
__device__ __forceinline__ float block_sum(float v, float* red, int tid) {
#pragma unroll
    for (int m = 32; m >= 1; m >>= 1) v += __shfl_xor(v, m, 64);
    __syncthreads();
    if ((tid & 63) == 0) red[tid >> 6] = v;
    __syncthreads();
    return red[0] + red[1] + red[2] + red[3];
}

__global__ __launch_bounds__(256) void head_kernel(const float* __restrict__ xcat,
                                                   const float* __restrict__ fc1w,
                                                   const float* __restrict__ fc1b,
                                                   const float* __restrict__ lng,
                                                   const float* __restrict__ lnb,
                                                   const float* __restrict__ fc2w,
                                                   const float* __restrict__ fc2b,
                                                   float* __restrict__ out) {
    __shared__ float xr[600];
    __shared__ float red[4];
    int b = blockIdx.x, tid = threadIdx.x;
    for (int t = tid; t < 600; t += 256) xr[t] = xcat[b * 600 + t];
    __syncthreads();
    float h0 = fc1b[tid], h1 = fc1b[tid + 256];
    for (int k = 0; k < 600; ++k) {
        float xv = xr[k];
        h0 = fmaf(xv, fc1w[k * kLIN + tid], h0);
        h1 = fmaf(xv, fc1w[k * kLIN + tid + 256], h1);
    }
    float mu = block_sum(h0 + h1, red, tid) * (1.0f / kLIN);
    float d0 = h0 - mu, d1 = h1 - mu;
    float var = block_sum(d0 * d0 + d1 * d1, red, tid) * (1.0f / kLIN);
    float rstd = rsqrtf(var + 1e-5f);
    float n0 = d0 * rstd * lng[tid] + lnb[tid];
    float n1 = d1 * rstd * lng[tid + 256] + lnb[tid + 256];
    float r0 = fmaxf(n0, 0.f), r1 = fmaxf(n1, 0.f);
    float p0 = r0 * fc2w[tid * 2 + 0] + r1 * fc2w[(tid + 256) * 2 + 0];
    float p1 = r0 * fc2w[tid * 2 + 1] + r1 * fc2w[(tid + 256) * 2 + 1];
    float o0 = block_sum(p0, red, tid);
    float o1 = block_sum(p1, red, tid);
    if (tid == 0) { out[b * 2 + 0] = o0 + fc2b[0]; out[b * 2 + 1] = o1 + fc2b[1]; }
}

// ----------------------------------------------------------------------------
extern "C" void kernel_launch(void* const* d_in, const int* in_sizes, int n_in,
                              void* d_out, int out_size, void* d_ws, size_t ws_size,
                              hipStream_t stream) {
    const int*   q1   = (const int*)d_in[0];
    const int*   q2   = (const int*)d_in[1];
    const float* emb  = (const float*)d_in[2];
    const float* Ws   = (const float*)d_in[3];
    const float* ck   = (const float*)d_in[4];
    const float* cb   = (const float*)d_in[5];
    const float* fc1w = (const float*)d_in[6];
    const float* fc1b = (const float*)d_in[7];
    const float* lng  = (const float*)d_in[8];
    const float* lnb  = (const float*)d_in[9];
    const float* fc2w = (const float*)d_in[10];
    const float* fc2b = (const float*)d_in[11];
    float* out = (float*)d_out;
    float* ws  = (float*)d_ws;

    float* e1  = ws;
    float* e2  = e1 + SZ_E;
    unsigned short* fb1 = (unsigned short*)(e2 + SZ_E);   // f1|f2 bf16 = SZ_E floats total
    unsigned short* fb2 = fb1 + SZ_E;
    float* o1  = (float*)fb1 + SZ_E;
    float* o2  = o1 + SZ_E;
    unsigned short* sbf1 = (unsigned short*)(o2 + SZ_E);  // hi-only fragments, 2 sides
    unsigned short* sbf2 = sbf1 + kB * kL * 128;
    float* after = (float*)sbf1 + kB * kL * 128;
    unsigned short* Wfrag = (unsigned short*)after;
    float* sq1 = after + W_FRAG;
    float* sq2 = sq1 + kB * kL;
    float* w1  = sq2 + kB * kL;
    float* w2  = w1 + kB * kL;
    float* xcat = w2 + kB * kL;

    hipMemsetAsync(xcat, 0, kB * 600 * sizeof(float), stream);
    embprep_kernel<<<dim3(kB * kL / 16, 2), 256, 0, stream>>>(q1, q2, emb, e1, e2,
                                                              sbf1, sbf2, sq1, sq2, xcat);
    wprep_kernel<<<2, 256, 0, stream>>>(Ws, Wfrag);

    // ---- layer 0
    matchf_kernel<<<dim3(2, 2, kB), 256, 0, stream>>>(sbf1, sbf2, sq1, sq2, Wfrag, fb1, fb2);
    conv_kernel<<<dim3(kL / 16, kB, 2), 256, 0, stream>>>(e1, e2, fb1, fb2, ck, cb,
                                                          o1, o2, xcat, 100, 400,
                                                          1, 1, q1, q2, sbf1, sbf2, sq1, sq2, w1, w2);
    match_sums<<<dim3(2, 2, kB), 256, 0, stream>>>(sbf1, sbf2, sq1, sq2, w1, w2);
    poolprep_kernel<<<dim3(kB * kL / 16, 2), 256, 0, stream>>>(o1, o2, w1, w2, q1, q2,
                                                               e1, e2, sbf1, sbf2, sq1, sq2);
    // ---- layer 1 (tail match/pool dead; o-store also dead)
    matchf_kernel<<<dim3(2, 2, kB), 256, 0, stream>>>(sbf1, sbf2, sq1, sq2, Wfrag + W_FRAG, fb1, fb2);
    conv_kernel<<<dim3(kL / 16, kB, 2), 256, 0, stream>>>(e1, e2, fb1, fb2, ck + 18, cb + 1,
                                                          o1, o2, xcat, 200, 500,
                                                          0, 0, q1, q2, sbf1, sbf2, sq1, sq2, w1, w2);

    head_kernel<<<kB, 256, 0, stream>>>(xcat, fc1w, fc1b, lng, lnb, fc2w, fc2b, out);
}

// Round 12
// 376.789 us; speedup vs baseline: 1.0719x; 1.0199x over previous
//
#include <hip/hip_runtime.h>
#include <hip/hip_bf16.h>
#include <math.h>

// Problem constants
static constexpr int kB = 256;
static constexpr int kL = 256;
static constexpr int kD = 100;
static constexpr int kLIN = 512;
static constexpr int SZ_E = kB * kL * kD;     // 6,553,600
static constexpr int W_FRAG = 7 * 8 * 64 * 8; // 28672 bf16 per layer

typedef short  s8_t  __attribute__((ext_vector_type(8)));
typedef float  f4_t  __attribute__((ext_vector_type(4)));

// sbf fragment storage (hi-only bf16): rowgroup g = row>>4, slot s in [0,4):
//   ((size_t)g*4 + s)*512 shorts, lane = quad*16 + (row&15), 8 shorts/lane,
//   k = s*32 + quad*8 + j (identity). sq from the SAME bf16-rounded values.
// W fragments pi-permuted (wprep); matchf's Dp registers are A-operand
// fragments in the same pi order, fed directly to the f-GEMM MFMA.
// conv staging (r12): shifted-address global loads (component-aligned only)
// feed ALIGNED b128 LDS stores of the halo layout — no shuffles, no scalar
// stores, no 8-way conflicts. o is stored bf16 (only poolprep reads it).

__device__ __forceinline__ unsigned short f2bf(float x) {
    __hip_bfloat16 h = __float2bfloat16(x);
    return *(unsigned short*)&h;
}
__device__ __forceinline__ float bf2f(unsigned short u) {
    unsigned int w = ((unsigned int)u) << 16;
    return *(float*)&w;
}
__device__ __forceinline__ float ftanh(float x) {
    float ax = fabsf(x);
    float t = __expf(-2.f * ax);
    float r = 1.f - 2.f * t / (1.f + t);
    return copysignf(r, x);
}

// write one rowgroup (16 rows in rb[16][104]) as 4 coalesced hi fragments (one per wave)
__device__ __forceinline__ void frag_store(const float (*rb)[104], const float* vsh,
                                           unsigned short* sb, int g, int tid) {
    int lane = tid & 63, wave = tid >> 6;   // wave = slot
    int qd = (lane >> 4) & 3, r15 = lane & 15;
    float v = vsh[r15];
    int kbase = wave * 32 + qd * 8;
    s8_t stv;
#pragma unroll
    for (int j = 0; j < 8; ++j) {
        int k = kbase + j;
        float x = (k < kD) ? rb[r15][k] * v : 0.f;
        stv[j] = (short)f2bf(x);
    }
    *(s8_t*)(sb + ((size_t)g * 4 + wave) * 512 + lane * 8) = stv;
}

// per-row sum of squares of bf16-ROUNDED masked values (16 threads/row)
__device__ __forceinline__ void sq_store(const float (*rb)[104], const float* vsh,
                                         float* sq, int row0, int tid) {
    int r = tid >> 4, j = tid & 15;
    float v = vsh[r];
    float s = 0.f;
    for (int d = j; d < kD; d += 16) { float x = bf2f(f2bf(rb[r][d] * v)); s += x * x; }
#pragma unroll
    for (int m = 8; m >= 1; m >>= 1) s += __shfl_xor(s, m, 64);
    if (j == 0) sq[row0 + r] = s;
}

// ------------------------------------------------------------- embed + prep + fused mean
__global__ __launch_bounds__(256) void embprep_kernel(const int* __restrict__ q1,
                                                      const int* __restrict__ q2,
                                                      const float* __restrict__ emb,
                                                      float* __restrict__ e1,
                                                      float* __restrict__ e2,
                                                      unsigned short* __restrict__ sbf1,
                                                      unsigned short* __restrict__ sbf2,
                                                      float* __restrict__ sq1,
                                                      float* __restrict__ sq2,
                                                      float* __restrict__ xcat) {
    __shared__ float rb[16][104];
    __shared__ float vsh[16];
    int side = blockIdx.y;
    const int* q = side ? q2 : q1;
    float* e = side ? e2 : e1;
    unsigned short* sb = side ? sbf2 : sbf1;
    float* sq = side ? sq2 : sq1;
    int tid = threadIdx.x;
    int row0 = blockIdx.x * 16;
    int b = row0 >> 8;
    if (tid < 16) vsh[tid] = (q[row0 + tid] != 0) ? 1.f : 0.f;
    for (int t = tid; t < 400; t += 256) {
        int r = t / 25, c = t - r * 25;
        int qv = q[row0 + r];
        float4 v4 = *(const float4*)(emb + (size_t)qv * kD + c * 4);
        *(float4*)(e + (size_t)(row0 + r) * kD + c * 4) = v4;
        *(float4*)&rb[r][c * 4] = v4;
    }
    __syncthreads();
    sq_store(rb, vsh, sq, row0, tid);
    if (tid < kD) {
        float s = 0.f;
#pragma unroll
        for (int r = 0; r < 16; ++r) s += rb[r][tid];
        atomicAdd(&xcat[b * 600 + side * 300 + tid], s * (1.0f / kL));
    }
    frag_store(rb, vsh, sb, row0 >> 4, tid);
}

// ------------------------------------------------------------- fused match + f-GEMM
__global__ __launch_bounds__(256) void matchf_kernel(const unsigned short* __restrict__ sbf1,
                                                     const unsigned short* __restrict__ sbf2,
                                                     const float* __restrict__ sq1,
                                                     const float* __restrict__ sq2,
                                                     const unsigned short* __restrict__ Wf,
                                                     unsigned short* __restrict__ f1,
                                                     unsigned short* __restrict__ f2) {
    __shared__ short lb[8 * 4 * 512];   // 32KB: contraction-side fragments
    int tid = threadIdx.x;
    int lane = tid & 63, wave = tid >> 6;
    int quad = lane >> 4, l15 = lane & 15;
    int side = blockIdx.y;
    int b = blockIdx.z;
    const unsigned short* sA = side ? sbf2 : sbf1;
    const unsigned short* sB = side ? sbf1 : sbf2;
    const float* sqA = side ? sq2 : sq1;
    const float* sqB = side ? sq1 : sq2;
    unsigned short* fo = side ? f2 : f1;
    int i0 = blockIdx.x * 128;
    int iw = i0 + wave * 32;
    int lo8 = lane * 8;

    const unsigned short* s1f = sA + ((size_t)(b * 16 + (iw >> 4)) * 4) * 512 + lo8;
    s8_t a1[2][4];
#pragma unroll
    for (int mt = 0; mt < 2; ++mt)
#pragma unroll
        for (int kt = 0; kt < 4; ++kt)
            a1[mt][kt] = *(const s8_t*)(s1f + (size_t)(mt * 4 + kt) * 512);

    float s1c[2] = { sqA[b * kL + iw + l15], sqA[b * kL + iw + 16 + l15] };
    const float* sq2p = sqB + b * kL;

    f4_t facc[2][7] = {};

    for (int jt = 0; jt < 2; ++jt) {
        int j0 = jt * 128;
        if (jt) __syncthreads();
        const unsigned short* s2base = sB + ((size_t)(b * 16 + (j0 >> 4)) * 4) * 512;
#pragma unroll
        for (int t = 0; t < 8; ++t) {
            int frag = wave * 8 + t;
            s8_t vld = *(const s8_t*)(s2base + (size_t)frag * 512 + lo8);
            *(s8_t*)(lb + frag * 512 + lo8) = vld;
        }
        __syncthreads();
#pragma unroll
        for (int half = 0; half < 2; ++half) {
            f4_t Dp[4][2] = {};
#pragma unroll
            for (int kt = 0; kt < 4; ++kt) {
                s8_t b2[4];
#pragma unroll
                for (int n = 0; n < 4; ++n)
                    b2[n] = *(const s8_t*)&lb[((half * 4 + n) * 4 + kt) * 512 + lo8];
#pragma unroll
                for (int n = 0; n < 4; ++n)
#pragma unroll
                    for (int mt = 0; mt < 2; ++mt)
                        Dp[n][mt] = __builtin_amdgcn_mfma_f32_16x16x32_bf16(b2[n], a1[mt][kt], Dp[n][mt], 0, 0, 0);
            }
#pragma unroll
            for (int np = 0; np < 2; ++np) {
                int ktj = (j0 >> 5) + half * 2 + np;
                const unsigned short* bp = Wf + (size_t)(ktj * 64 + lane) * 8;
#pragma unroll
                for (int mt = 0; mt < 2; ++mt) {
                    s8_t af;
#pragma unroll
                    for (int h2 = 0; h2 < 2; ++h2) {
                        int n = np * 2 + h2;
#pragma unroll
                        for (int r = 0; r < 4; ++r) {
                            float s2q = sq2p[j0 + half * 64 + n * 16 + quad * 4 + r];
                            float d2 = fmaxf(s2q + s1c[mt] - 2.f * Dp[n][mt][r], 0.f);
                            float av = __builtin_amdgcn_rcpf(1.f + __builtin_amdgcn_sqrtf(d2));
                            af[h2 * 4 + r] = (short)f2bf(av);
                        }
                    }
#pragma unroll
                    for (int nt = 0; nt < 7; ++nt) {
                        s8_t wv = *(const s8_t*)(bp + (size_t)nt * 8 * 64 * 8);
                        facc[mt][nt] = __builtin_amdgcn_mfma_f32_16x16x32_bf16(af, wv, facc[mt][nt], 0, 0, 0);
                    }
                }
            }
        }
    }
#pragma unroll
    for (int mt = 0; mt < 2; ++mt)
#pragma unroll
        for (int nt = 0; nt < 7; ++nt) {
            int col = nt * 16 + l15;
            if (col < kD) {
#pragma unroll
                for (int r = 0; r < 4; ++r) {
                    size_t row = (size_t)(b * kL) + iw + mt * 16 + quad * 4 + r;
                    fo[row * kD + col] = f2bf(facc[mt][nt][r]);
                }
            }
        }
}

// ------------------------------------------------------------- match row/col sums (pooling weights)
__global__ __launch_bounds__(256) void match_sums(const unsigned short* __restrict__ sbf1,
                                                  const unsigned short* __restrict__ sbf2,
                                                  const float* __restrict__ sq1,
                                                  const float* __restrict__ sq2,
                                                  float* __restrict__ w1,
                                                  float* __restrict__ w2) {
    __shared__ short lb[8 * 4 * 512];
    int tid = threadIdx.x;
    int lane = tid & 63, wave = tid >> 6;
    int quad = lane >> 4, l15 = lane & 15;
    int b = blockIdx.z;
    int i0 = blockIdx.y * 128, j0 = blockIdx.x * 128;
    int iw = i0 + wave * 32;
    int lo8 = lane * 8;

    const unsigned short* s2base = sbf2 + ((size_t)(b * 16 + (j0 >> 4)) * 4) * 512;
#pragma unroll
    for (int t = 0; t < 8; ++t) {
        int frag = wave * 8 + t;
        s8_t vld = *(const s8_t*)(s2base + (size_t)frag * 512 + lo8);
        *(s8_t*)(lb + frag * 512 + lo8) = vld;
    }

    const unsigned short* s1f = sbf1 + ((size_t)(b * 16 + (iw >> 4)) * 4) * 512 + lo8;
    const float* sq1p = sq1 + b * kL + iw;
    const float* sq2p = sq2 + b * kL + j0;

    float s1v[2][4];
#pragma unroll
    for (int mt = 0; mt < 2; ++mt)
#pragma unroll
        for (int r = 0; r < 4; ++r) s1v[mt][r] = sq1p[mt * 16 + quad * 4 + r];

    float rs_acc[2][4] = {{0.f,0.f,0.f,0.f},{0.f,0.f,0.f,0.f}};
    __syncthreads();

    for (int half = 0; half < 2; ++half) {
        f4_t D[2][4] = {};
#pragma unroll
        for (int kt = 0; kt < 4; ++kt) {
            s8_t a1h[2], b2h[4];
#pragma unroll
            for (int mt = 0; mt < 2; ++mt)
                a1h[mt] = *(const s8_t*)(s1f + (size_t)(mt * 4 + kt) * 512);
#pragma unroll
            for (int n = 0; n < 4; ++n)
                b2h[n] = *(const s8_t*)&lb[((half * 4 + n) * 4 + kt) * 512 + lo8];
#pragma unroll
            for (int mt = 0; mt < 2; ++mt)
#pragma unroll
                for (int n = 0; n < 4; ++n)
                    D[mt][n] = __builtin_amdgcn_mfma_f32_16x16x32_bf16(a1h[mt], b2h[n], D[mt][n], 0, 0, 0);
        }
#pragma unroll
        for (int n = 0; n < 4; ++n) {
            float s2vn = sq2p[half * 64 + n * 16 + l15];
            float cs = 0.f;
#pragma unroll
            for (int mt = 0; mt < 2; ++mt) {
#pragma unroll
                for (int r = 0; r < 4; ++r) {
                    float d2 = fmaxf(s1v[mt][r] + s2vn - 2.f * D[mt][n][r], 0.f);
                    float av = __builtin_amdgcn_rcpf(1.f + __builtin_amdgcn_sqrtf(d2));
                    rs_acc[mt][r] += av; cs += av;
                }
            }
            cs += __shfl_xor(cs, 16, 64);
            cs += __shfl_xor(cs, 32, 64);
            if (lane < 16) atomicAdd(&w2[b * kL + j0 + half * 64 + n * 16 + lane], cs);
        }
    }
#pragma unroll
    for (int mt = 0; mt < 2; ++mt)
#pragma unroll
        for (int r = 0; r < 4; ++r) {
            float v = rs_acc[mt][r];
            v += __shfl_xor(v, 1, 64);
            v += __shfl_xor(v, 2, 64);
            v += __shfl_xor(v, 4, 64);
            v += __shfl_xor(v, 8, 64);
            if (l15 == 0) atomicAdd(&w1[b * kL + iw + mt * 16 + quad * 4 + r], v);
        }
}

// ------------------------------------------------------------- W -> B-fragment layout (bf16, pi-permuted k)
__global__ __launch_bounds__(256) void wprep_kernel(const float* __restrict__ Ws,
                                                    unsigned short* __restrict__ Wf) {
    int layer = blockIdx.x;
    const float* W = Ws + layer * kL * kD;
    unsigned short* o = Wf + layer * W_FRAG;
    for (int t = threadIdx.x; t < W_FRAG; t += 256) {
        int j = t & 7, lane = (t >> 3) & 63, kt = (t >> 9) & 7, nt = t >> 12;
        int k = kt * 32 + (j >> 2) * 16 + ((lane >> 4) & 3) * 4 + (j & 3);  // pi
        int n = nt * 16 + (lane & 15);
        float v = (n < kD) ? W[k * kD + n] : 0.f;
        o[t] = f2bf(v);
    }
}

// ------------------------------------------------------------- conv(3x3, 2ch) + tanh + mean(1) [+ fused hi prep]
// r12 staging: shifted-address global loads -> aligned b128 LDS stores of the
// halo layout [r][1+d]. Compute loop identical to r8. o is bf16.
__global__ __launch_bounds__(256) void conv_kernel(const float* __restrict__ e1,
                                                   const float* __restrict__ e2,
                                                   const unsigned short* __restrict__ f1,
                                                   const unsigned short* __restrict__ f2,
                                                   const float* __restrict__ ck,
                                                   const float* __restrict__ cb,
                                                   unsigned short* __restrict__ o1,
                                                   unsigned short* __restrict__ o2,
                                                   float* __restrict__ res,
                                                   int ro1, int ro2,
                                                   int do_prep, int do_store,
                                                   const int* __restrict__ q1,
                                                   const int* __restrict__ q2,
                                                   unsigned short* __restrict__ sbf1,
                                                   unsigned short* __restrict__ sbf2,
                                                   float* __restrict__ sq1,
                                                   float* __restrict__ sq2,
                                                   float* __restrict__ w1,
                                                   float* __restrict__ w2) {
    __shared__ float le[18][104];
    __shared__ float lf[18][104];
    __shared__ float pm[8][104];
    __shared__ float ksh[19];
    int tid = threadIdx.x;
    int b = blockIdx.y;
    int l0 = blockIdx.x * 16;
    int side = blockIdx.z;
    const float* e = side ? e2 : e1;
    const unsigned short* f = side ? f2 : f1;
    unsigned short* o = side ? o2 : o1;
    const int* q = side ? q2 : q1;
    unsigned short* sb = side ? sbf2 : sbf1;
    float* sq = side ? sq2 : sq1;
    float* w = side ? w2 : w1;
    int res_off = side ? ro2 : ro1;
    if (tid < 19) ksh[tid] = (tid < 18) ? ck[tid] : cb[0];
    if (do_prep && tid < 16) w[b * kL + l0 + tid] = 0.f;
    // staging: 18 rows x 26 slots x 2 channels; slot c covers halo words [4c..4c+3]
    // = data[4c-1 .. 4c+2], loaded in one shot from global at elem offset 4c-1.
    for (int t = tid; t < 936; t += 256) {
        int a = t >= 468;
        int tt = a ? t - 468 : t;
        int r = tt / 26, c = tt - r * 26;
        int l = l0 - 1 + r;
        float4 v = {0.f, 0.f, 0.f, 0.f};
        if (l >= 0 && l < kL) {
            size_t base = ((size_t)b * kL + l) * kD + c * 4 - 1;
            if (!a) v = *(const float4*)(e + base);
            else { ushort4 u = *(const ushort4*)(f + base);
                   v.x = bf2f(u.x); v.y = bf2f(u.y); v.z = bf2f(u.z); v.w = bf2f(u.w); }
            if (c == 0) v.x = 0.f;
            if (c == 25) { v.y = 0.f; v.z = 0.f; v.w = 0.f; }
        }
        float* rowp = a ? lf[r] : le[r];
        *(float4*)&rowp[c * 4] = v;
    }
    __syncthreads();
    int rg = tid >> 5, c4 = tid & 31;
    bool act = c4 < 25;
    int d0 = c4 * 4;
    float m4[4] = {0.f, 0.f, 0.f, 0.f};
#pragma unroll
    for (int rr = 0; rr < 2; ++rr) {
        int r = rg * 2 + rr;
        float a0 = 0.f, a1 = 0.f, a2 = 0.f, a3 = 0.f;
        if (act) {
            float bias = ksh[18];
            a0 = bias; a1 = bias; a2 = bias; a3 = bias;
#pragma unroll
            for (int ch = 0; ch < 2; ++ch) {
                const float (*L)[104] = ch ? lf : le;
                const float* kp = &ksh[ch * 9];
#pragma unroll
                for (int ky = 0; ky < 3; ++ky) {
                    const float* row = L[r + ky];
                    float4 v4 = *(const float4*)&row[d0];
                    float2 v2 = *(const float2*)&row[d0 + 4];
                    float k0 = kp[ky * 3], k1 = kp[ky * 3 + 1], k2 = kp[ky * 3 + 2];
                    a0 += k0 * v4.x + k1 * v4.y + k2 * v4.z;
                    a1 += k0 * v4.y + k1 * v4.z + k2 * v4.w;
                    a2 += k0 * v4.z + k1 * v4.w + k2 * v2.x;
                    a3 += k0 * v4.w + k1 * v2.x + k2 * v2.y;
                }
            }
            a0 = ftanh(a0); a1 = ftanh(a1); a2 = ftanh(a2); a3 = ftanh(a3);
            if (do_store) {
                ushort4 st = {f2bf(a0), f2bf(a1), f2bf(a2), f2bf(a3)};
                *(ushort4*)&o[((size_t)(b * kL) + l0 + r) * kD + d0] = st;
            }
            m4[0] += a0; m4[1] += a1; m4[2] += a2; m4[3] += a3;
        }
        if (do_prep) {
            int row = b * kL + l0 + r;
            float v = (q[row] != 0) ? 1.f : 0.f;
            ushort4 hi = {0, 0, 0, 0};
            float xr0 = 0.f, xr1 = 0.f, xr2 = 0.f, xr3 = 0.f;
            if (act) {
                hi.x = f2bf(a0 * v); xr0 = bf2f(hi.x);
                hi.y = f2bf(a1 * v); xr1 = bf2f(hi.y);
                hi.z = f2bf(a2 * v); xr2 = bf2f(hi.z);
                hi.w = f2bf(a3 * v); xr3 = bf2f(hi.w);
            }
            float srow = xr0 * xr0 + xr1 * xr1 + xr2 * xr2 + xr3 * xr3;
#pragma unroll
            for (int m = 16; m >= 1; m >>= 1) srow += __shfl_xor(srow, m, 32);
            if (c4 == 0) sq[row] = srow;
            int kt = c4 >> 3;
            int lfr = ((c4 >> 1) & 3) * 16 + (row & 15);
            unsigned short* p0 = sb + ((size_t)(row >> 4) * 4 + kt) * 512 + lfr * 8 + 4 * (c4 & 1);
            *(ushort4*)p0 = hi;
        }
    }
    if (act) { float4 st = {m4[0], m4[1], m4[2], m4[3]}; *(float4*)&pm[rg][d0] = st; }
    __syncthreads();
    if (tid < kD) {
        float s = 0.f;
#pragma unroll
        for (int g = 0; g < 8; ++g) s += pm[g][tid];
        atomicAdd(&res[b * 600 + res_off + tid], s * (1.0f / kL));
    }
}

// ------------------------------------------------------------- fused: e += avgpool3(o*w); hi prep (16-row blocks)
__global__ __launch_bounds__(256) void poolprep_kernel(const unsigned short* __restrict__ o1,
                                                       const unsigned short* __restrict__ o2,
                                                       const float* __restrict__ w1_,
                                                       const float* __restrict__ w2_,
                                                       const int* __restrict__ q1,
                                                       const int* __restrict__ q2,
                                                       float* __restrict__ e1,
                                                       float* __restrict__ e2,
                                                       unsigned short* __restrict__ sbf1,
                                                       unsigned short* __restrict__ sbf2,
                                                       float* __restrict__ sq1,
                                                       float* __restrict__ sq2) {
    __shared__ float tb[18][104];
    __shared__ float xb[16][104];
    __shared__ float vsh[16];
    __shared__ float wsh[18];
    int side = blockIdx.y;
    const unsigned short* o = side ? o2 : o1;
    const float* w = side ? w2_ : w1_;
    const int* q = side ? q2 : q1;
    float* e = side ? e2 : e1;
    unsigned short* sb = side ? sbf2 : sbf1;
    float* sq = side ? sq2 : sq1;
    int tid = threadIdx.x;
    int row0 = blockIdx.x * 16;
    int l0 = row0 & (kL - 1);
    int base_b = row0 - l0;
    if (tid < 18) {
        int l = l0 - 1 + tid;
        wsh[tid] = (l >= 0 && l < kL) ? w[base_b + l] : 0.f;
    }
    if (tid < 16) vsh[tid] = (q[row0 + tid] != 0) ? 1.f : 0.f;
    __syncthreads();
    for (int t = tid; t < 450; t += 256) {
        int r = t / 25, c = t - r * 25;
        int l = l0 - 1 + r;
        float4 v4 = {0.f, 0.f, 0.f, 0.f};
        if (l >= 0 && l < kL) {
            ushort4 u = *(const ushort4*)(o + (size_t)(base_b + l) * kD + c * 4);
            v4.x = bf2f(u.x); v4.y = bf2f(u.y); v4.z = bf2f(u.z); v4.w = bf2f(u.w);
        }
        float ww = wsh[r];
        tb[r][c * 4 + 0] = v4.x * ww;
        tb[r][c * 4 + 1] = v4.y * ww;
        tb[r][c * 4 + 2] = v4.z * ww;
        tb[r][c * 4 + 3] = v4.w * ww;
    }
    __syncthreads();
    for (int t = tid; t < 400; t += 256) {
        int r = t / 25, c = t - r * 25;
        float* ep = e + (size_t)(row0 + r) * kD + c * 4;
        float4 e4 = *(float4*)ep;
        float nx = e4.x + (tb[r][c * 4 + 0] + tb[r + 1][c * 4 + 0] + tb[r + 2][c * 4 + 0]) * (1.f / 3.f);
        float ny = e4.y + (tb[r][c * 4 + 1] + tb[r + 1][c * 4 + 1] + tb[r + 2][c * 4 + 1]) * (1.f / 3.f);
        float nz = e4.z + (tb[r][c * 4 + 2] + tb[r + 1][c * 4 + 2] + tb[r + 2][c * 4 + 2]) * (1.f / 3.f);
        float nw = e4.w + (tb[r][c * 4 + 3] + tb[r + 1][c * 4 + 3] + tb[r + 2][c * 4 + 3]) * (1.f / 3.f);
        float4 st = {nx, ny, nz, nw};
        *(float4*)ep = st;
        *(float4*)&xb[r][c * 4] = st;
    }
    __syncthreads();
    sq_store(xb, vsh, sq, row0, tid);
    frag_store(xb, vsh, sb, row0 >> 4, tid);
}

// ------------------------------------------------------------- head
__device__ __forceinline__ float block_sum(float v, float* red, int tid) {
#pragma unroll
    for (int m = 32; m >= 1; m >>= 1) v += __shfl_xor(v, m, 64);
    __syncthreads();
    if ((tid & 63) == 0) red[tid >> 6] = v;
    __syncthreads();
    return red[0] + red[1] + red[2] + red[3];
}

__global__ __launch_bounds__(256) void head_kernel(const float* __restrict__ xcat,
                                                   const float* __restrict__ fc1w,
                                                   const float* __restrict__ fc1b,
                                                   const float* __restrict__ lng,
                                                   const float* __restrict__ lnb,
                                                   const float* __restrict__ fc2w,
                                                   const float* __restrict__ fc2b,
                                                   float* __restrict__ out) {
    __shared__ float xr[600];
    __shared__ float red[4];
    int b = blockIdx.x, tid = threadIdx.x;
    for (int t = tid; t < 600; t += 256) xr[t] = xcat[b * 600 + t];
    __syncthreads();
    float h0 = fc1b[tid], h1 = fc1b[tid + 256];
    for (int k = 0; k < 600; ++k) {
        float xv = xr[k];
        h0 = fmaf(xv, fc1w[k * kLIN + tid], h0);
        h1 = fmaf(xv, fc1w[k * kLIN + tid + 256], h1);
    }
    float mu = block_sum(h0 + h1, red, tid) * (1.0f / kLIN);
    float d0 = h0 - mu, d1 = h1 - mu;
    float var = block_sum(d0 * d0 + d1 * d1, red, tid) * (1.0f / kLIN);
    float rstd = rsqrtf(var + 1e-5f);
    float n0 = d0 * rstd * lng[tid] + lnb[tid];
    float n1 = d1 * rstd * lng[tid + 256] + lnb[tid + 256];
    float r0 = fmaxf(n0, 0.f), r1 = fmaxf(n1, 0.f);
    float p0 = r0 * fc2w[tid * 2 + 0] + r1 * fc2w[(tid + 256) * 2 + 0];
    float p1 = r0 * fc2w[tid * 2 + 1] + r1 * fc2w[(tid + 256) * 2 + 1];
    float o0 = block_sum(p0, red, tid);
    float o1 = block_sum(p1, red, tid);
    if (tid == 0) { out[b * 2 + 0] = o0 + fc2b[0]; out[b * 2 + 1] = o1 + fc2b[1]; }
}

// ----------------------------------------------------------------------------
extern "C" void kernel_launch(void* const* d_in, const int* in_sizes, int n_in,
                              void* d_out, int out_size, void* d_ws, size_t ws_size,
                              hipStream_t stream) {
    const int*   q1   = (const int*)d_in[0];
    const int*   q2   = (const int*)d_in[1];
    const float* emb  = (const float*)d_in[2];
    const float* Ws   = (const float*)d_in[3];
    const float* ck   = (const float*)d_in[4];
    const float* cb   = (const float*)d_in[5];
    const float* fc1w = (const float*)d_in[6];
    const float* fc1b = (const float*)d_in[7];
    const float* lng  = (const float*)d_in[8];
    const float* lnb  = (const float*)d_in[9];
    const float* fc2w = (const float*)d_in[10];
    const float* fc2b = (const float*)d_in[11];
    float* out = (float*)d_out;
    float* ws  = (float*)d_ws;

    float* e1  = ws + 16;                                 // +16 guard: staging reads e-4B
    float* e2  = e1 + SZ_E;
    unsigned short* fb1 = (unsigned short*)(e2 + SZ_E);   // f1|f2 bf16 = SZ_E floats total
    unsigned short* fb2 = fb1 + SZ_E;
    unsigned short* o1  = (unsigned short*)((float*)fb1 + SZ_E);  // o bf16, SZ_E floats total
    unsigned short* o2  = o1 + SZ_E;
    unsigned short* sbf1 = (unsigned short*)((float*)o1 + SZ_E);  // hi-only fragments, 2 sides
    unsigned short* sbf2 = sbf1 + kB * kL * 128;
    float* after = (float*)sbf1 + kB * kL * 128;
    unsigned short* Wfrag = (unsigned short*)after;
    float* sq1 = after + W_FRAG;
    float* sq2 = sq1 + kB * kL;
    float* w1  = sq2 + kB * kL;
    float* w2  = w1 + kB * kL;
    float* xcat = w2 + kB * kL;

    hipMemsetAsync(xcat, 0, kB * 600 * sizeof(float), stream);
    embprep_kernel<<<dim3(kB * kL / 16, 2), 256, 0, stream>>>(q1, q2, emb, e1, e2,
                                                              sbf1, sbf2, sq1, sq2, xcat);
    wprep_kernel<<<2, 256, 0, stream>>>(Ws, Wfrag);

    // ---- layer 0
    matchf_kernel<<<dim3(2, 2, kB), 256, 0, stream>>>(sbf1, sbf2, sq1, sq2, Wfrag, fb1, fb2);
    conv_kernel<<<dim3(kL / 16, kB, 2), 256, 0, stream>>>(e1, e2, fb1, fb2, ck, cb,
                                                          o1, o2, xcat, 100, 400,
                                                          1, 1, q1, q2, sbf1, sbf2, sq1, sq2, w1, w2);
    match_sums<<<dim3(2, 2, kB), 256, 0, stream>>>(sbf1, sbf2, sq1, sq2, w1, w2);
    poolprep_kernel<<<dim3(kB * kL / 16, 2), 256, 0, stream>>>(o1, o2, w1, w2, q1, q2,
                                                               e1, e2, sbf1, sbf2, sq1, sq2);
    // ---- layer 1 (tail match/pool dead; o-store also dead)
    matchf_kernel<<<dim3(2, 2, kB), 256, 0, stream>>>(sbf1, sbf2, sq1, sq2, Wfrag + W_FRAG, fb1, fb2);
    conv_kernel<<<dim3(kL / 16, kB, 2), 256, 0, stream>>>(e1, e2, fb1, fb2, ck + 18, cb + 1,
                                                          o1, o2, xcat, 200, 500,
                                                          0, 0, q1, q2, sbf1, sbf2, sq1, sq2, w1, w2);

    head_kernel<<<kB, 256, 0, stream>>>(xcat, fc1w, fc1b, lng, lnb, fc2w, fc2b, out);
}

// Round 13
// 341.466 us; speedup vs baseline: 1.1828x; 1.1034x over previous
//
#include <hip/hip_runtime.h>
#include <hip/hip_bf16.h>
#include <math.h>

// Problem constants
static constexpr int kB = 256;
static constexpr int kL = 256;
static constexpr int kD = 100;
static constexpr int kLIN = 512;
static constexpr int SZ_E = kB * kL * kD;     // 6,553,600
static constexpr int W_FRAG = 7 * 8 * 64 * 8; // 28672 bf16 per layer

typedef short  s8_t  __attribute__((ext_vector_type(8)));
typedef float  f4_t  __attribute__((ext_vector_type(4)));

// sbf fragment storage (hi-only bf16): rowgroup g = row>>4, slot s in [0,4):
//   ((size_t)g*4 + s)*512 shorts, lane = quad*16 + (row&15), 8 shorts/lane,
//   k = s*32 + quad*8 + j (identity). sq from the SAME bf16-rounded values.
// W fragments pi-permuted (wprep); matchf's Dp registers are A-operand
// fragments in the same pi order, fed directly to the f-GEMM MFMA.
// conv staging (r12): shifted-address global loads feed ALIGNED b128 LDS
// stores of the halo layout. o is bf16. wprep (r13): 1 elem/thread — the
// 2-block loop version was 47.8us of pure latency serialization.

__device__ __forceinline__ unsigned short f2bf(float x) {
    __hip_bfloat16 h = __float2bfloat16(x);
    return *(unsigned short*)&h;
}
__device__ __forceinline__ float bf2f(unsigned short u) {
    unsigned int w = ((unsigned int)u) << 16;
    return *(float*)&w;
}
__device__ __forceinline__ float ftanh(float x) {
    float ax = fabsf(x);
    float t = __expf(-2.f * ax);
    float r = 1.f - 2.f * t / (1.f + t);
    return copysignf(r, x);
}

// write one rowgroup (16 rows in rb[16][104]) as 4 coalesced hi fragments (one per wave)
__device__ __forceinline__ void frag_store(const float (*rb)[104], const float* vsh,
                                           unsigned short* sb, int g, int tid) {
    int lane = tid & 63, wave = tid >> 6;   // wave = slot
    int qd = (lane >> 4) & 3, r15 = lane & 15;
    float v = vsh[r15];
    int kbase = wave * 32 + qd * 8;
    s8_t stv;
#pragma unroll
    for (int j = 0; j < 8; ++j) {
        int k = kbase + j;
        float x = (k < kD) ? rb[r15][k] * v : 0.f;
        stv[j] = (short)f2bf(x);
    }
    *(s8_t*)(sb + ((size_t)g * 4 + wave) * 512 + lane * 8) = stv;
}

// per-row sum of squares of bf16-ROUNDED masked values (16 threads/row)
__device__ __forceinline__ void sq_store(const float (*rb)[104], const float* vsh,
                                         float* sq, int row0, int tid) {
    int r = tid >> 4, j = tid & 15;
    float v = vsh[r];
    float s = 0.f;
    for (int d = j; d < kD; d += 16) { float x = bf2f(f2bf(rb[r][d] * v)); s += x * x; }
#pragma unroll
    for (int m = 8; m >= 1; m >>= 1) s += __shfl_xor(s, m, 64);
    if (j == 0) sq[row0 + r] = s;
}

// ------------------------------------------------------------- embed + prep + fused mean
__global__ __launch_bounds__(256) void embprep_kernel(const int* __restrict__ q1,
                                                      const int* __restrict__ q2,
                                                      const float* __restrict__ emb,
                                                      float* __restrict__ e1,
                                                      float* __restrict__ e2,
                                                      unsigned short* __restrict__ sbf1,
                                                      unsigned short* __restrict__ sbf2,
                                                      float* __restrict__ sq1,
                                                      float* __restrict__ sq2,
                                                      float* __restrict__ xcat) {
    __shared__ float rb[16][104];
    __shared__ float vsh[16];
    int side = blockIdx.y;
    const int* q = side ? q2 : q1;
    float* e = side ? e2 : e1;
    unsigned short* sb = side ? sbf2 : sbf1;
    float* sq = side ? sq2 : sq1;
    int tid = threadIdx.x;
    int row0 = blockIdx.x * 16;
    int b = row0 >> 8;
    if (tid < 16) vsh[tid] = (q[row0 + tid] != 0) ? 1.f : 0.f;
    for (int t = tid; t < 400; t += 256) {
        int r = t / 25, c = t - r * 25;
        int qv = q[row0 + r];
        float4 v4 = *(const float4*)(emb + (size_t)qv * kD + c * 4);
        *(float4*)(e + (size_t)(row0 + r) * kD + c * 4) = v4;
        *(float4*)&rb[r][c * 4] = v4;
    }
    __syncthreads();
    sq_store(rb, vsh, sq, row0, tid);
    if (tid < kD) {
        float s = 0.f;
#pragma unroll
        for (int r = 0; r < 16; ++r) s += rb[r][tid];
        atomicAdd(&xcat[b * 600 + side * 300 + tid], s * (1.0f / kL));
    }
    frag_store(rb, vsh, sb, row0 >> 4, tid);
}

// ------------------------------------------------------------- fused match + f-GEMM
__global__ __launch_bounds__(256) void matchf_kernel(const unsigned short* __restrict__ sbf1,
                                                     const unsigned short* __restrict__ sbf2,
                                                     const float* __restrict__ sq1,
                                                     const float* __restrict__ sq2,
                                                     const unsigned short* __restrict__ Wf,
                                                     unsigned short* __restrict__ f1,
                                                     unsigned short* __restrict__ f2) {
    __shared__ short lb[8 * 4 * 512];   // 32KB: contraction-side fragments
    int tid = threadIdx.x;
    int lane = tid & 63, wave = tid >> 6;
    int quad = lane >> 4, l15 = lane & 15;
    int side = blockIdx.y;
    int b = blockIdx.z;
    const unsigned short* sA = side ? sbf2 : sbf1;
    const unsigned short* sB = side ? sbf1 : sbf2;
    const float* sqA = side ? sq2 : sq1;
    const float* sqB = side ? sq1 : sq2;
    unsigned short* fo = side ? f2 : f1;
    int i0 = blockIdx.x * 128;
    int iw = i0 + wave * 32;
    int lo8 = lane * 8;

    const unsigned short* s1f = sA + ((size_t)(b * 16 + (iw >> 4)) * 4) * 512 + lo8;
    s8_t a1[2][4];
#pragma unroll
    for (int mt = 0; mt < 2; ++mt)
#pragma unroll
        for (int kt = 0; kt < 4; ++kt)
            a1[mt][kt] = *(const s8_t*)(s1f + (size_t)(mt * 4 + kt) * 512);

    float s1c[2] = { sqA[b * kL + iw + l15], sqA[b * kL + iw + 16 + l15] };
    const float* sq2p = sqB + b * kL;

    f4_t facc[2][7] = {};

    for (int jt = 0; jt < 2; ++jt) {
        int j0 = jt * 128;
        if (jt) __syncthreads();
        const unsigned short* s2base = sB + ((size_t)(b * 16 + (j0 >> 4)) * 4) * 512;
#pragma unroll
        for (int t = 0; t < 8; ++t) {
            int frag = wave * 8 + t;
            s8_t vld = *(const s8_t*)(s2base + (size_t)frag * 512 + lo8);
            *(s8_t*)(lb + frag * 512 + lo8) = vld;
        }
        __syncthreads();
#pragma unroll
        for (int half = 0; half < 2; ++half) {
            f4_t Dp[4][2] = {};
#pragma unroll
            for (int kt = 0; kt < 4; ++kt) {
                s8_t b2[4];
#pragma unroll
                for (int n = 0; n < 4; ++n)
                    b2[n] = *(const s8_t*)&lb[((half * 4 + n) * 4 + kt) * 512 + lo8];
#pragma unroll
                for (int n = 0; n < 4; ++n)
#pragma unroll
                    for (int mt = 0; mt < 2; ++mt)
                        Dp[n][mt] = __builtin_amdgcn_mfma_f32_16x16x32_bf16(b2[n], a1[mt][kt], Dp[n][mt], 0, 0, 0);
            }
#pragma unroll
            for (int np = 0; np < 2; ++np) {
                int ktj = (j0 >> 5) + half * 2 + np;
                const unsigned short* bp = Wf + (size_t)(ktj * 64 + lane) * 8;
#pragma unroll
                for (int mt = 0; mt < 2; ++mt) {
                    s8_t af;
#pragma unroll
                    for (int h2 = 0; h2 < 2; ++h2) {
                        int n = np * 2 + h2;
#pragma unroll
                        for (int r = 0; r < 4; ++r) {
                            float s2q = sq2p[j0 + half * 64 + n * 16 + quad * 4 + r];
                            float d2 = fmaxf(s2q + s1c[mt] - 2.f * Dp[n][mt][r], 0.f);
                            float av = __builtin_amdgcn_rcpf(1.f + __builtin_amdgcn_sqrtf(d2));
                            af[h2 * 4 + r] = (short)f2bf(av);
                        }
                    }
#pragma unroll
                    for (int nt = 0; nt < 7; ++nt) {
                        s8_t wv = *(const s8_t*)(bp + (size_t)nt * 8 * 64 * 8);
                        facc[mt][nt] = __builtin_amdgcn_mfma_f32_16x16x32_bf16(af, wv, facc[mt][nt], 0, 0, 0);
                    }
                }
            }
        }
    }
#pragma unroll
    for (int mt = 0; mt < 2; ++mt)
#pragma unroll
        for (int nt = 0; nt < 7; ++nt) {
            int col = nt * 16 + l15;
            if (col < kD) {
#pragma unroll
                for (int r = 0; r < 4; ++r) {
                    size_t row = (size_t)(b * kL) + iw + mt * 16 + quad * 4 + r;
                    fo[row * kD + col] = f2bf(facc[mt][nt][r]);
                }
            }
        }
}

// ------------------------------------------------------------- match row/col sums (pooling weights)
__global__ __launch_bounds__(256) void match_sums(const unsigned short* __restrict__ sbf1,
                                                  const unsigned short* __restrict__ sbf2,
                                                  const float* __restrict__ sq1,
                                                  const float* __restrict__ sq2,
                                                  float* __restrict__ w1,
                                                  float* __restrict__ w2) {
    __shared__ short lb[8 * 4 * 512];
    int tid = threadIdx.x;
    int lane = tid & 63, wave = tid >> 6;
    int quad = lane >> 4, l15 = lane & 15;
    int b = blockIdx.z;
    int i0 = blockIdx.y * 128, j0 = blockIdx.x * 128;
    int iw = i0 + wave * 32;
    int lo8 = lane * 8;

    const unsigned short* s2base = sbf2 + ((size_t)(b * 16 + (j0 >> 4)) * 4) * 512;
#pragma unroll
    for (int t = 0; t < 8; ++t) {
        int frag = wave * 8 + t;
        s8_t vld = *(const s8_t*)(s2base + (size_t)frag * 512 + lo8);
        *(s8_t*)(lb + frag * 512 + lo8) = vld;
    }

    const unsigned short* s1f = sbf1 + ((size_t)(b * 16 + (iw >> 4)) * 4) * 512 + lo8;
    const float* sq1p = sq1 + b * kL + iw;
    const float* sq2p = sq2 + b * kL + j0;

    float s1v[2][4];
#pragma unroll
    for (int mt = 0; mt < 2; ++mt)
#pragma unroll
        for (int r = 0; r < 4; ++r) s1v[mt][r] = sq1p[mt * 16 + quad * 4 + r];

    float rs_acc[2][4] = {{0.f,0.f,0.f,0.f},{0.f,0.f,0.f,0.f}};
    __syncthreads();

    for (int half = 0; half < 2; ++half) {
        f4_t D[2][4] = {};
#pragma unroll
        for (int kt = 0; kt < 4; ++kt) {
            s8_t a1h[2], b2h[4];
#pragma unroll
            for (int mt = 0; mt < 2; ++mt)
                a1h[mt] = *(const s8_t*)(s1f + (size_t)(mt * 4 + kt) * 512);
#pragma unroll
            for (int n = 0; n < 4; ++n)
                b2h[n] = *(const s8_t*)&lb[((half * 4 + n) * 4 + kt) * 512 + lo8];
#pragma unroll
            for (int mt = 0; mt < 2; ++mt)
#pragma unroll
                for (int n = 0; n < 4; ++n)
                    D[mt][n] = __builtin_amdgcn_mfma_f32_16x16x32_bf16(a1h[mt], b2h[n], D[mt][n], 0, 0, 0);
        }
#pragma unroll
        for (int n = 0; n < 4; ++n) {
            float s2vn = sq2p[half * 64 + n * 16 + l15];
            float cs = 0.f;
#pragma unroll
            for (int mt = 0; mt < 2; ++mt) {
#pragma unroll
                for (int r = 0; r < 4; ++r) {
                    float d2 = fmaxf(s1v[mt][r] + s2vn - 2.f * D[mt][n][r], 0.f);
                    float av = __builtin_amdgcn_rcpf(1.f + __builtin_amdgcn_sqrtf(d2));
                    rs_acc[mt][r] += av; cs += av;
                }
            }
            cs += __shfl_xor(cs, 16, 64);
            cs += __shfl_xor(cs, 32, 64);
            if (lane < 16) atomicAdd(&w2[b * kL + j0 + half * 64 + n * 16 + lane], cs);
        }
    }
#pragma unroll
    for (int mt = 0; mt < 2; ++mt)
#pragma unroll
        for (int r = 0; r < 4; ++r) {
            float v = rs_acc[mt][r];
            v += __shfl_xor(v, 1, 64);
            v += __shfl_xor(v, 2, 64);
            v += __shfl_xor(v, 4, 64);
            v += __shfl_xor(v, 8, 64);
            if (l15 == 0) atomicAdd(&w1[b * kL + iw + mt * 16 + quad * 4 + r], v);
        }
}

// ------------------------------------------------------------- W -> B-fragment layout (bf16, pi-permuted k)
// r13: one element per thread (the 2-block loop form was latency-serialized).
__global__ __launch_bounds__(256) void wprep_kernel(const float* __restrict__ Ws,
                                                    unsigned short* __restrict__ Wf) {
    int layer = blockIdx.y;
    int t = blockIdx.x * 256 + threadIdx.x;   // grid.x = W_FRAG / 256 = 112
    const float* W = Ws + layer * kL * kD;
    unsigned short* o = Wf + layer * W_FRAG;
    int j = t & 7, lane = (t >> 3) & 63, kt = (t >> 9) & 7, nt = t >> 12;
    int k = kt * 32 + (j >> 2) * 16 + ((lane >> 4) & 3) * 4 + (j & 3);  // pi
    int n = nt * 16 + (lane & 15);
    float v = (n < kD) ? W[k * kD + n] : 0.f;
    o[t] = f2bf(v);
}

// ------------------------------------------------------------- conv(3x3, 2ch) + tanh + mean(1) [+ fused hi prep]
// r12 staging: shifted-address global loads -> aligned b128 LDS stores of the
// halo layout [r][1+d]. Compute loop identical to r8. o is bf16.
__global__ __launch_bounds__(256) void conv_kernel(const float* __restrict__ e1,
                                                   const float* __restrict__ e2,
                                                   const unsigned short* __restrict__ f1,
                                                   const unsigned short* __restrict__ f2,
                                                   const float* __restrict__ ck,
                                                   const float* __restrict__ cb,
                                                   unsigned short* __restrict__ o1,
                                                   unsigned short* __restrict__ o2,
                                                   float* __restrict__ res,
                                                   int ro1, int ro2,
                                                   int do_prep, int do_store,
                                                   const int* __restrict__ q1,
                                                   const int* __restrict__ q2,
                                                   unsigned short* __restrict__ sbf1,
                                                   unsigned short* __restrict__ sbf2,
                                                   float* __restrict__ sq1,
                                                   float* __restrict__ sq2,
                                                   float* __restrict__ w1,
                                                   float* __restrict__ w2) {
    __shared__ float le[18][104];
    __shared__ float lf[18][104];
    __shared__ float pm[8][104];
    __shared__ float ksh[19];
    int tid = threadIdx.x;
    int b = blockIdx.y;
    int l0 = blockIdx.x * 16;
    int side = blockIdx.z;
    const float* e = side ? e2 : e1;
    const unsigned short* f = side ? f2 : f1;
    unsigned short* o = side ? o2 : o1;
    const int* q = side ? q2 : q1;
    unsigned short* sb = side ? sbf2 : sbf1;
    float* sq = side ? sq2 : sq1;
    float* w = side ? w2 : w1;
    int res_off = side ? ro2 : ro1;
    if (tid < 19) ksh[tid] = (tid < 18) ? ck[tid] : cb[0];
    if (do_prep && tid < 16) w[b * kL + l0 + tid] = 0.f;
    for (int t = tid; t < 936; t += 256) {
        int a = t >= 468;
        int tt = a ? t - 468 : t;
        int r = tt / 26, c = tt - r * 26;
        int l = l0 - 1 + r;
        float4 v = {0.f, 0.f, 0.f, 0.f};
        if (l >= 0 && l < kL) {
            size_t base = ((size_t)b * kL + l) * kD + c * 4 - 1;
            if (!a) v = *(const float4*)(e + base);
            else { ushort4 u = *(const ushort4*)(f + base);
                   v.x = bf2f(u.x); v.y = bf2f(u.y); v.z = bf2f(u.z); v.w = bf2f(u.w); }
            if (c == 0) v.x = 0.f;
            if (c == 25) { v.y = 0.f; v.z = 0.f; v.w = 0.f; }
        }
        float* rowp = a ? lf[r] : le[r];
        *(float4*)&rowp[c * 4] = v;
    }
    __syncthreads();
    int rg = tid >> 5, c4 = tid & 31;
    bool act = c4 < 25;
    int d0 = c4 * 4;
    float m4[4] = {0.f, 0.f, 0.f, 0.f};
#pragma unroll
    for (int rr = 0; rr < 2; ++rr) {
        int r = rg * 2 + rr;
        float a0 = 0.f, a1 = 0.f, a2 = 0.f, a3 = 0.f;
        if (act) {
            float bias = ksh[18];
            a0 = bias; a1 = bias; a2 = bias; a3 = bias;
#pragma unroll
            for (int ch = 0; ch < 2; ++ch) {
                const float (*L)[104] = ch ? lf : le;
                const float* kp = &ksh[ch * 9];
#pragma unroll
                for (int ky = 0; ky < 3; ++ky) {
                    const float* row = L[r + ky];
                    float4 v4 = *(const float4*)&row[d0];
                    float2 v2 = *(const float2*)&row[d0 + 4];
                    float k0 = kp[ky * 3], k1 = kp[ky * 3 + 1], k2 = kp[ky * 3 + 2];
                    a0 += k0 * v4.x + k1 * v4.y + k2 * v4.z;
                    a1 += k0 * v4.y + k1 * v4.z + k2 * v4.w;
                    a2 += k0 * v4.z + k1 * v4.w + k2 * v2.x;
                    a3 += k0 * v4.w + k1 * v2.x + k2 * v2.y;
                }
            }
            a0 = ftanh(a0); a1 = ftanh(a1); a2 = ftanh(a2); a3 = ftanh(a3);
            if (do_store) {
                ushort4 st = {f2bf(a0), f2bf(a1), f2bf(a2), f2bf(a3)};
                *(ushort4*)&o[((size_t)(b * kL) + l0 + r) * kD + d0] = st;
            }
            m4[0] += a0; m4[1] += a1; m4[2] += a2; m4[3] += a3;
        }
        if (do_prep) {
            int row = b * kL + l0 + r;
            float v = (q[row] != 0) ? 1.f : 0.f;
            ushort4 hi = {0, 0, 0, 0};
            float xr0 = 0.f, xr1 = 0.f, xr2 = 0.f, xr3 = 0.f;
            if (act) {
                hi.x = f2bf(a0 * v); xr0 = bf2f(hi.x);
                hi.y = f2bf(a1 * v); xr1 = bf2f(hi.y);
                hi.z = f2bf(a2 * v); xr2 = bf2f(hi.z);
                hi.w = f2bf(a3 * v); xr3 = bf2f(hi.w);
            }
            float srow = xr0 * xr0 + xr1 * xr1 + xr2 * xr2 + xr3 * xr3;
#pragma unroll
            for (int m = 16; m >= 1; m >>= 1) srow += __shfl_xor(srow, m, 32);
            if (c4 == 0) sq[row] = srow;
            int kt = c4 >> 3;
            int lfr = ((c4 >> 1) & 3) * 16 + (row & 15);
            unsigned short* p0 = sb + ((size_t)(row >> 4) * 4 + kt) * 512 + lfr * 8 + 4 * (c4 & 1);
            *(ushort4*)p0 = hi;
        }
    }
    if (act) { float4 st = {m4[0], m4[1], m4[2], m4[3]}; *(float4*)&pm[rg][d0] = st; }
    __syncthreads();
    if (tid < kD) {
        float s = 0.f;
#pragma unroll
        for (int g = 0; g < 8; ++g) s += pm[g][tid];
        atomicAdd(&res[b * 600 + res_off + tid], s * (1.0f / kL));
    }
}

// ------------------------------------------------------------- fused: e += avgpool3(o*w); hi prep (16-row blocks)
__global__ __launch_bounds__(256) void poolprep_kernel(const unsigned short* __restrict__ o1,
                                                       const unsigned short* __restrict__ o2,
                                                       const float* __restrict__ w1_,
                                                       const float* __restrict__ w2_,
                                                       const int* __restrict__ q1,
                                                       const int* __restrict__ q2,
                                                       float* __restrict__ e1,
                                                       float* __restrict__ e2,
                                                       unsigned short* __restrict__ sbf1,
                                                       unsigned short* __restrict__ sbf2,
                                                       float* __restrict__ sq1,
                                                       float* __restrict__ sq2) {
    __shared__ float tb[18][104];
    __shared__ float xb[16][104];
    __shared__ float vsh[16];
    __shared__ float wsh[18];
    int side = blockIdx.y;
    const unsigned short* o = side ? o2 : o1;
    const float* w = side ? w2_ : w1_;
    const int* q = side ? q2 : q1;
    float* e = side ? e2 : e1;
    unsigned short* sb = side ? sbf2 : sbf1;
    float* sq = side ? sq2 : sq1;
    int tid = threadIdx.x;
    int row0 = blockIdx.x * 16;
    int l0 = row0 & (kL - 1);
    int base_b = row0 - l0;
    if (tid < 18) {
        int l = l0 - 1 + tid;
        wsh[tid] = (l >= 0 && l < kL) ? w[base_b + l] : 0.f;
    }
    if (tid < 16) vsh[tid] = (q[row0 + tid] != 0) ? 1.f : 0.f;
    __syncthreads();
    for (int t = tid; t < 450; t += 256) {
        int r = t / 25, c = t - r * 25;
        int l = l0 - 1 + r;
        float4 v4 = {0.f, 0.f, 0.f, 0.f};
        if (l >= 0 && l < kL) {
            ushort4 u = *(const ushort4*)(o + (size_t)(base_b + l) * kD + c * 4);
            v4.x = bf2f(u.x); v4.y = bf2f(u.y); v4.z = bf2f(u.z); v4.w = bf2f(u.w);
        }
        float ww = wsh[r];
        tb[r][c * 4 + 0] = v4.x * ww;
        tb[r][c * 4 + 1] = v4.y * ww;
        tb[r][c * 4 + 2] = v4.z * ww;
        tb[r][c * 4 + 3] = v4.w * ww;
    }
    __syncthreads();
    for (int t = tid; t < 400; t += 256) {
        int r = t / 25, c = t - r * 25;
        float* ep = e + (size_t)(row0 + r) * kD + c * 4;
        float4 e4 = *(float4*)ep;
        float nx = e4.x + (tb[r][c * 4 + 0] + tb[r + 1][c * 4 + 0] + tb[r + 2][c * 4 + 0]) * (1.f / 3.f);
        float ny = e4.y + (tb[r][c * 4 + 1] + tb[r + 1][c * 4 + 1] + tb[r + 2][c * 4 + 1]) * (1.f / 3.f);
        float nz = e4.z + (tb[r][c * 4 + 2] + tb[r + 1][c * 4 + 2] + tb[r + 2][c * 4 + 2]) * (1.f / 3.f);
        float nw = e4.w + (tb[r][c * 4 + 3] + tb[r + 1][c * 4 + 3] + tb[r + 2][c * 4 + 3]) * (1.f / 3.f);
        float4 st = {nx, ny, nz, nw};
        *(float4*)ep = st;
        *(float4*)&xb[r][c * 4] = st;
    }
    __syncthreads();
    sq_store(xb, vsh, sq, row0, tid);
    frag_store(xb, vsh, sb, row0 >> 4, tid);
}

// ------------------------------------------------------------- head
__device__ __forceinline__ float block_sum(float v, float* red, int tid) {
#pragma unroll
    for (int m = 32; m >= 1; m >>= 1) v += __shfl_xor(v, m, 64);
    __syncthreads();
    if ((tid & 63) == 0) red[tid >> 6] = v;
    __syncthreads();
    return red[0] + red[1] + red[2] + red[3];
}

__global__ __launch_bounds__(256) void head_kernel(const float* __restrict__ xcat,
                                                   const float* __restrict__ fc1w,
                                                   const float* __restrict__ fc1b,
                                                   const float* __restrict__ lng,
                                                   const float* __restrict__ lnb,
                                                   const float* __restrict__ fc2w,
                                                   const float* __restrict__ fc2b,
                                                   float* __restrict__ out) {
    __shared__ float xr[600];
    __shared__ float red[4];
    int b = blockIdx.x, tid = threadIdx.x;
    for (int t = tid; t < 600; t += 256) xr[t] = xcat[b * 600 + t];
    __syncthreads();
    float h0 = fc1b[tid], h1 = fc1b[tid + 256];
    for (int k = 0; k < 600; ++k) {
        float xv = xr[k];
        h0 = fmaf(xv, fc1w[k * kLIN + tid], h0);
        h1 = fmaf(xv, fc1w[k * kLIN + tid + 256], h1);
    }
    float mu = block_sum(h0 + h1, red, tid) * (1.0f / kLIN);
    float d0 = h0 - mu, d1 = h1 - mu;
    float var = block_sum(d0 * d0 + d1 * d1, red, tid) * (1.0f / kLIN);
    float rstd = rsqrtf(var + 1e-5f);
    float n0 = d0 * rstd * lng[tid] + lnb[tid];
    float n1 = d1 * rstd * lng[tid + 256] + lnb[tid + 256];
    float r0 = fmaxf(n0, 0.f), r1 = fmaxf(n1, 0.f);
    float p0 = r0 * fc2w[tid * 2 + 0] + r1 * fc2w[(tid + 256) * 2 + 0];
    float p1 = r0 * fc2w[tid * 2 + 1] + r1 * fc2w[(tid + 256) * 2 + 1];
    float o0 = block_sum(p0, red, tid);
    float o1 = block_sum(p1, red, tid);
    if (tid == 0) { out[b * 2 + 0] = o0 + fc2b[0]; out[b * 2 + 1] = o1 + fc2b[1]; }
}

// ----------------------------------------------------------------------------
extern "C" void kernel_launch(void* const* d_in, const int* in_sizes, int n_in,
                              void* d_out, int out_size, void* d_ws, size_t ws_size,
                              hipStream_t stream) {
    const int*   q1   = (const int*)d_in[0];
    const int*   q2   = (const int*)d_in[1];
    const float* emb  = (const float*)d_in[2];
    const float* Ws   = (const float*)d_in[3];
    const float* ck   = (const float*)d_in[4];
    const float* cb   = (const float*)d_in[5];
    const float* fc1w = (const float*)d_in[6];
    const float* fc1b = (const float*)d_in[7];
    const float* lng  = (const float*)d_in[8];
    const float* lnb  = (const float*)d_in[9];
    const float* fc2w = (const float*)d_in[10];
    const float* fc2b = (const float*)d_in[11];
    float* out = (float*)d_out;
    float* ws  = (float*)d_ws;

    float* e1  = ws + 16;                                 // +16 guard: staging reads e-4B
    float* e2  = e1 + SZ_E;
    unsigned short* fb1 = (unsigned short*)(e2 + SZ_E);   // f1|f2 bf16 = SZ_E floats total
    unsigned short* fb2 = fb1 + SZ_E;
    unsigned short* o1  = (unsigned short*)((float*)fb1 + SZ_E);  // o bf16, SZ_E floats total
    unsigned short* o2  = o1 + SZ_E;
    unsigned short* sbf1 = (unsigned short*)((float*)o1 + SZ_E);  // hi-only fragments, 2 sides
    unsigned short* sbf2 = sbf1 + kB * kL * 128;
    float* after = (float*)sbf1 + kB * kL * 128;
    unsigned short* Wfrag = (unsigned short*)after;
    float* sq1 = after + W_FRAG;
    float* sq2 = sq1 + kB * kL;
    float* w1  = sq2 + kB * kL;
    float* w2  = w1 + kB * kL;
    float* xcat = w2 + kB * kL;

    hipMemsetAsync(xcat, 0, kB * 600 * sizeof(float), stream);
    wprep_kernel<<<dim3(W_FRAG / 256, 2), 256, 0, stream>>>(Ws, Wfrag);
    embprep_kernel<<<dim3(kB * kL / 16, 2), 256, 0, stream>>>(q1, q2, emb, e1, e2,
                                                              sbf1, sbf2, sq1, sq2, xcat);

    // ---- layer 0
    matchf_kernel<<<dim3(2, 2, kB), 256, 0, stream>>>(sbf1, sbf2, sq1, sq2, Wfrag, fb1, fb2);
    conv_kernel<<<dim3(kL / 16, kB, 2), 256, 0, stream>>>(e1, e2, fb1, fb2, ck, cb,
                                                          o1, o2, xcat, 100, 400,
                                                          1, 1, q1, q2, sbf1, sbf2, sq1, sq2, w1, w2);
    match_sums<<<dim3(2, 2, kB), 256, 0, stream>>>(sbf1, sbf2, sq1, sq2, w1, w2);
    poolprep_kernel<<<dim3(kB * kL / 16, 2), 256, 0, stream>>>(o1, o2, w1, w2, q1, q2,
                                                               e1, e2, sbf1, sbf2, sq1, sq2);
    // ---- layer 1 (tail match/pool dead; o-store also dead)
    matchf_kernel<<<dim3(2, 2, kB), 256, 0, stream>>>(sbf1, sbf2, sq1, sq2, Wfrag + W_FRAG, fb1, fb2);
    conv_kernel<<<dim3(kL / 16, kB, 2), 256, 0, stream>>>(e1, e2, fb1, fb2, ck + 18, cb + 1,
                                                          o1, o2, xcat, 200, 500,
                                                          0, 0, q1, q2, sbf1, sbf2, sq1, sq2, w1, w2);

    head_kernel<<<kB, 256, 0, stream>>>(xcat, fc1w, fc1b, lng, lnb, fc2w, fc2b, out);
}